// Round 5
// baseline (778.288 us; speedup 1.0000x reference)
//
#include <hip/hip_runtime.h>
#include <hip/hip_cooperative_groups.h>
#include <cmath>

namespace cg = cooperative_groups;

#define NN 2048
#define EPSF 0.1f
#define K2 14.426950408889634f   /* (1/eps) * log2(e) */
#define LN2F 0.6931471805599453f

// ws layout (floats)
#define V_OFF    0                  // 2048
#define DU_OFF   2048               // 2048
#define DONE_OFF 4096               // 1 (+pad)
#define PM_OFF   4160               // 256 * 2048
#define PS_OFF   (4160 + 256 * NN) // 256 * 2048

__device__ __forceinline__ float fexp2(float x) { return __builtin_amdgcn_exp2f(x); }
__device__ __forceinline__ float flog2(float x) { return __builtin_amdgcn_logf(x); }

// online logsumexp combine in base-2 domain
__device__ __forceinline__ void lse_combine(float& M, float& S, float m, float s) {
    float mn = fmaxf(M, m);
    S = S * fexp2(M - mn) + s * fexp2(m - mn);
    M = mn;
}

// One persistent kernel: C in registers, 2 grid syncs per Sinkhorn iteration.
// 256 blocks x 512 threads. Block b: rows [8b,8b+8). Thread t: cols 4t..4t+3.
__global__ __launch_bounds__(512) void sink_all(
        const float* __restrict__ x, const float* __restrict__ y,
        float* __restrict__ cost, float* __restrict__ pi,
        float* __restrict__ Cout, float* __restrict__ ws, float log_mu)
{
    cg::grid_group grid = cg::this_grid();
    const int tid = threadIdx.x;
    const int b   = blockIdx.x;
    const int w   = tid >> 6, l = tid & 63;
    const int r0  = b * 8;
    const int j0  = 4 * tid;

    float* v_g  = ws + V_OFF;
    float* du   = ws + DU_OFF;
    float* done = ws + DONE_OFF;
    float* pm   = ws + PM_OFF;
    float* ps   = ws + PS_OFF;

    __shared__ float wsm[8][8], wss[8][8], uK_lds[8], sl[8];

    if (b == 0 && tid == 0) { cost[0] = 0.f; done[0] = 0.f; }

    // ---- phase 0: C tile in registers: acc[r][c] = C[r0+r][j0+c] ----
    const float4* x4 = (const float4*)x;
    const float4* y4 = (const float4*)y;
    float acc[8][4];
#pragma unroll
    for (int r = 0; r < 8; ++r)
#pragma unroll
        for (int c = 0; c < 4; ++c) acc[r][c] = 0.f;

    for (int d4 = 0; d4 < 16; ++d4) {
        float4 yv0 = y4[(size_t)(j0 + 0) * 16 + d4];
        float4 yv1 = y4[(size_t)(j0 + 1) * 16 + d4];
        float4 yv2 = y4[(size_t)(j0 + 2) * 16 + d4];
        float4 yv3 = y4[(size_t)(j0 + 3) * 16 + d4];
#pragma unroll
        for (int r = 0; r < 8; ++r) {
            float4 xv = x4[(size_t)(r0 + r) * 16 + d4];  // wave-uniform
            float d0, d1, d2, d3;
            d0 = xv.x - yv0.x; d1 = xv.y - yv0.y; d2 = xv.z - yv0.z; d3 = xv.w - yv0.w;
            acc[r][0] = fmaf(d0, d0, fmaf(d1, d1, fmaf(d2, d2, fmaf(d3, d3, acc[r][0]))));
            d0 = xv.x - yv1.x; d1 = xv.y - yv1.y; d2 = xv.z - yv1.z; d3 = xv.w - yv1.w;
            acc[r][1] = fmaf(d0, d0, fmaf(d1, d1, fmaf(d2, d2, fmaf(d3, d3, acc[r][1]))));
            d0 = xv.x - yv2.x; d1 = xv.y - yv2.y; d2 = xv.z - yv2.z; d3 = xv.w - yv2.w;
            acc[r][2] = fmaf(d0, d0, fmaf(d1, d1, fmaf(d2, d2, fmaf(d3, d3, acc[r][2]))));
            d0 = xv.x - yv3.x; d1 = xv.y - yv3.y; d2 = xv.z - yv3.z; d3 = xv.w - yv3.w;
            acc[r][3] = fmaf(d0, d0, fmaf(d1, d1, fmaf(d2, d2, fmaf(d3, d3, acc[r][3]))));
        }
    }

    // ---- Sinkhorn iterations ----
    float u_old = 0.f;      // valid for tid < 8 (row r0+tid)
    bool active = true;

    for (int it = 0; it < 10; ++it) {
        if (active) {
            float vK[4];
            if (it == 0) {
                vK[0] = vK[1] = vK[2] = vK[3] = 0.f;
            } else {
                float4 vv = *(const float4*)(v_g + j0);
                vK[0] = vv.x * K2; vK[1] = vv.y * K2;
                vK[2] = vv.z * K2; vK[3] = vv.w * K2;
            }

            // row phase: max
            float m8[8];
#pragma unroll
            for (int r = 0; r < 8; ++r) {
                float a0 = fmaf(-K2, acc[r][0], vK[0]);
                float a1 = fmaf(-K2, acc[r][1], vK[1]);
                float a2 = fmaf(-K2, acc[r][2], vK[2]);
                float a3 = fmaf(-K2, acc[r][3], vK[3]);
                m8[r] = fmaxf(fmaxf(a0, a1), fmaxf(a2, a3));
            }
#pragma unroll
            for (int off = 1; off < 64; off <<= 1)
#pragma unroll
                for (int r = 0; r < 8; ++r)
                    m8[r] = fmaxf(m8[r], __shfl_xor(m8[r], off));
            if (l == 0)
#pragma unroll
                for (int r = 0; r < 8; ++r) wsm[w][r] = m8[r];
            __syncthreads();
            float M8[8];
#pragma unroll
            for (int r = 0; r < 8; ++r) {
                float q0 = fmaxf(wsm[0][r], wsm[1][r]);
                float q1 = fmaxf(wsm[2][r], wsm[3][r]);
                float q2 = fmaxf(wsm[4][r], wsm[5][r]);
                float q3 = fmaxf(wsm[6][r], wsm[7][r]);
                M8[r] = fmaxf(fmaxf(q0, q1), fmaxf(q2, q3));
            }

            // row phase: sum
            float s8[8];
#pragma unroll
            for (int r = 0; r < 8; ++r) {
                float a0 = fmaf(-K2, acc[r][0], vK[0]) - M8[r];
                float a1 = fmaf(-K2, acc[r][1], vK[1]) - M8[r];
                float a2 = fmaf(-K2, acc[r][2], vK[2]) - M8[r];
                float a3 = fmaf(-K2, acc[r][3], vK[3]) - M8[r];
                s8[r] = (fexp2(a0) + fexp2(a1)) + (fexp2(a2) + fexp2(a3));
            }
#pragma unroll
            for (int off = 1; off < 64; off <<= 1)
#pragma unroll
                for (int r = 0; r < 8; ++r)
                    s8[r] += __shfl_xor(s8[r], off);
            if (l == 0)
#pragma unroll
                for (int r = 0; r < 8; ++r) wss[w][r] = s8[r];
            __syncthreads();
            if (tid < 8) {
                float S = ((wss[0][tid] + wss[1][tid]) + (wss[2][tid] + wss[3][tid]))
                        + ((wss[4][tid] + wss[5][tid]) + (wss[6][tid] + wss[7][tid]));
                float un = EPSF * (log_mu - LN2F * (M8[tid] + flog2(S)));
                du[r0 + tid] = fabsf(un - u_old);
                u_old = un;
                uK_lds[tid] = un * K2;
            }
            __syncthreads();
            float uKr[8];
#pragma unroll
            for (int r = 0; r < 8; ++r) uKr[r] = uK_lds[r];

            // col partials over this block's 8 rows
            float cm[4], cs[4];
#pragma unroll
            for (int c = 0; c < 4; ++c) {
                float b0 = fmaf(-K2, acc[0][c], uKr[0]);
                float b1 = fmaf(-K2, acc[1][c], uKr[1]);
                float b2 = fmaf(-K2, acc[2][c], uKr[2]);
                float b3 = fmaf(-K2, acc[3][c], uKr[3]);
                float b4 = fmaf(-K2, acc[4][c], uKr[4]);
                float b5 = fmaf(-K2, acc[5][c], uKr[5]);
                float b6 = fmaf(-K2, acc[6][c], uKr[6]);
                float b7 = fmaf(-K2, acc[7][c], uKr[7]);
                float m = fmaxf(fmaxf(fmaxf(b0, b1), fmaxf(b2, b3)),
                                fmaxf(fmaxf(b4, b5), fmaxf(b6, b7)));
                cm[c] = m;
                cs[c] = (fexp2(b0 - m) + fexp2(b1 - m)) + (fexp2(b2 - m) + fexp2(b3 - m))
                      + (fexp2(b4 - m) + fexp2(b5 - m)) + (fexp2(b6 - m) + fexp2(b7 - m));
            }
            *(float4*)(pm + (size_t)b * NN + j0) = make_float4(cm[0], cm[1], cm[2], cm[3]);
            *(float4*)(ps + (size_t)b * NN + j0) = make_float4(cs[0], cs[1], cs[2], cs[3]);
        }
        grid.sync();
        if (active) {
            // finish v: wave w of block b owns col 8b+w; lane handles 4 panels
            int col = 8 * b + w;
            float M = -INFINITY, S = 0.f;
#pragma unroll
            for (int k = 0; k < 4; ++k) {
                int p = l + 64 * k;
                lse_combine(M, S, pm[(size_t)p * NN + col], ps[(size_t)p * NN + col]);
            }
#pragma unroll
            for (int off = 1; off < 64; off <<= 1) {
                float mo = __shfl_xor(M, off);
                float so = __shfl_xor(S, off);
                lse_combine(M, S, mo, so);
            }
            if (l == 0) v_g[col] = EPSF * (log_mu - LN2F * (M + flog2(S)));

            if (b == 0) {
                float t = ((du[tid] + du[tid + 512]) + (du[tid + 1024] + du[tid + 1536]));
#pragma unroll
                for (int off = 1; off < 64; off <<= 1) t += __shfl_xor(t, off);
                if (l == 0) sl[w] = t;
                __syncthreads();
                if (tid == 0) {
                    float errv = ((sl[0] + sl[1]) + (sl[2] + sl[3]))
                               + ((sl[4] + sl[5]) + (sl[6] + sl[7]));
                    if (errv < 0.1f) done[0] = 1.f;
                }
            }
        }
        grid.sync();
        active = (done[0] == 0.f);
    }

    // ---- final: pi, Cout, cost ----
    float4 vv = *(const float4*)(v_g + j0);
    float vK0 = vv.x * K2, vK1 = vv.y * K2, vK2c = vv.z * K2, vK3 = vv.w * K2;
    float uKr[8];
#pragma unroll
    for (int r = 0; r < 8; ++r) uKr[r] = uK_lds[r];

    float costloc = 0.f;
#pragma unroll
    for (int r = 0; r < 8; ++r) {
        size_t base = (size_t)(r0 + r) * NN + j0;
        float c0 = acc[r][0], c1 = acc[r][1], c2 = acc[r][2], c3 = acc[r][3];
        float p0 = fexp2(fmaf(-K2, c0, uKr[r] + vK0));
        float p1 = fexp2(fmaf(-K2, c1, uKr[r] + vK1));
        float p2 = fexp2(fmaf(-K2, c2, uKr[r] + vK2c));
        float p3 = fexp2(fmaf(-K2, c3, uKr[r] + vK3));
        pi[base + 0] = p0; pi[base + 1] = p1; pi[base + 2] = p2; pi[base + 3] = p3;
        Cout[base + 0] = c0; Cout[base + 1] = c1; Cout[base + 2] = c2; Cout[base + 3] = c3;
        costloc = fmaf(p0, c0, costloc);
        costloc = fmaf(p1, c1, costloc);
        costloc = fmaf(p2, c2, costloc);
        costloc = fmaf(p3, c3, costloc);
    }
#pragma unroll
    for (int off = 1; off < 64; off <<= 1) costloc += __shfl_xor(costloc, off);
    if (l == 0) sl[w] = costloc;
    __syncthreads();
    if (tid == 0) {
        float t = ((sl[0] + sl[1]) + (sl[2] + sl[3])) + ((sl[4] + sl[5]) + (sl[6] + sl[7]));
        atomicAdd(cost, t);
    }
}

extern "C" void kernel_launch(void* const* d_in, const int* in_sizes, int n_in,
                              void* d_out, int out_size, void* d_ws, size_t ws_size,
                              hipStream_t stream) {
    const float* x = (const float*)d_in[0];
    const float* y = (const float*)d_in[1];
    float* out  = (float*)d_out;
    float* cost = out;                       // [0]
    float* pi   = out + 1;                   // [1 .. 1+2048*2048)
    float* Cout = out + 1 + (size_t)NN * NN; // [.. 1+2*2048*2048)
    float* ws   = (float*)d_ws;

    float log_mu = (float)log(1.0 / 2048.0 + 1e-8); // n == m -> log_nu == log_mu

    void* args[] = { (void*)&x, (void*)&y, (void*)&cost, (void*)&pi,
                     (void*)&Cout, (void*)&ws, (void*)&log_mu };
    hipLaunchCooperativeKernel((const void*)sink_all, dim3(256), dim3(512),
                               args, 0, stream);
}

// Round 6
// 456.209 us; speedup vs baseline: 1.7060x; 1.7060x over previous
//
#include <hip/hip_runtime.h>
#include <cmath>

#define NN 2048

#define EPSF 0.1f
#define K2 14.426950408889634f   /* (1/eps) * log2(e) */
#define LN2F 0.6931471805599453f

// ws layout (floats)
#define U_OFF   0
#define V_OFF   2048
#define ERR_OFF 4096
#define FLG_OFF 4112
#define DU_OFF  4128
#define CWS_OFF 6176
#define PM_OFF  (6176 + 2048*2048)
#define PS_OFF  (PM_OFF + 512*2048)

__device__ __forceinline__ float fexp2(float x) { return __builtin_amdgcn_exp2f(x); }
__device__ __forceinline__ float flog2(float x) { return __builtin_amdgcn_logf(x); }

// online logsumexp combine in base-2 domain: (M,S) <- (M,S) ++ (m,s)
__device__ __forceinline__ void lse_combine(float& M, float& S, float m, float s) {
    float mn = fmaxf(M, m);
    S = S * fexp2(M - mn) + s * fexp2(m - mn);
    M = mn;
}

// ---------------------------------------------------------------------------
// Kernel 1: C[i][j] = sum_d (x[i][d]-y[j][d])^2 -> Cout (output) + Cws (aligned)
// Also zero-inits u/v/err/flag/du and cost. grid (32, 16), block 256.
// ---------------------------------------------------------------------------
__global__ __launch_bounds__(256) void sink_cost_matrix(
        const float* __restrict__ x, const float* __restrict__ y,
        float* __restrict__ Cout, float* __restrict__ Cws,
        float* __restrict__ wsz, float* __restrict__ cost) {
    __shared__ float xs[128][65];
    __shared__ float ys[64][65];
    int tid = threadIdx.x;
    int bj = blockIdx.x, bi = blockIdx.y;

    if (bi == 0 && bj == 0) {
        // u(2048)+v(2048)+err(16)+flag(16)+du(2048) = 6176
        for (int k = tid; k < 6176; k += 256) wsz[k] = 0.f;
        if (tid == 0) cost[0] = 0.f;
    }

    const float4* x4 = (const float4*)x;
    const float4* y4 = (const float4*)y;
    for (int q = tid; q < 128 * 16; q += 256) {
        int r = q >> 4, dq = q & 15;
        float4 val = x4[(size_t)(bi * 128 + r) * 16 + dq];
        xs[r][dq * 4 + 0] = val.x; xs[r][dq * 4 + 1] = val.y;
        xs[r][dq * 4 + 2] = val.z; xs[r][dq * 4 + 3] = val.w;
    }
    for (int q = tid; q < 64 * 16; q += 256) {
        int r = q >> 4, dq = q & 15;
        float4 val = y4[(size_t)(bj * 64 + r) * 16 + dq];
        ys[r][dq * 4 + 0] = val.x; ys[r][dq * 4 + 1] = val.y;
        ys[r][dq * 4 + 2] = val.z; ys[r][dq * 4 + 3] = val.w;
    }
    __syncthreads();

    int tx = tid & 15, ty = tid >> 4;
    float acc[8][4];
#pragma unroll
    for (int ii = 0; ii < 8; ++ii)
#pragma unroll
        for (int jj = 0; jj < 4; ++jj) acc[ii][jj] = 0.f;

#pragma unroll 4
    for (int dd = 0; dd < 64; ++dd) {
        float xv[8], yv[4];
#pragma unroll
        for (int ii = 0; ii < 8; ++ii) xv[ii] = xs[ty + 16 * ii][dd];
#pragma unroll
        for (int jj = 0; jj < 4; ++jj) yv[jj] = ys[tx + 16 * jj][dd];
#pragma unroll
        for (int ii = 0; ii < 8; ++ii)
#pragma unroll
            for (int jj = 0; jj < 4; ++jj) {
                float d = xv[ii] - yv[jj];
                acc[ii][jj] = fmaf(d, d, acc[ii][jj]);
            }
    }

#pragma unroll
    for (int ii = 0; ii < 8; ++ii)
#pragma unroll
        for (int jj = 0; jj < 4; ++jj) {
            int gi = bi * 128 + ty + 16 * ii;
            int gj = bj * 64 + tx + 16 * jj;
            Cout[(size_t)gi * NN + gj] = acc[ii][jj];
            Cws [(size_t)gi * NN + gj] = acc[ii][jj];
        }
}

// ---------------------------------------------------------------------------
// Kernel 2 (per iter): ONE pass over C. grid 512, block 256 (2 blocks/CU).
// Block b owns rows [4b, 4b+4). Thread t owns cols {4t..4t+3, 1024+4t..+3}.
// Row phase: u_i update + du. Col phase: per-block col partials (m,s),
// panel-major pm/ps[b*2048 + j] (512 panels).
// Gate: flag[it-1] || err[it-1] < 0.1 -> publish flag[it], skip.
// ---------------------------------------------------------------------------
__global__ __launch_bounds__(256, 2) void sink_iter(
        const float* __restrict__ Cws, float* __restrict__ u,
        const float* __restrict__ v, float* __restrict__ du,
        const float* __restrict__ err, float* __restrict__ flag,
        float* __restrict__ pm, float* __restrict__ ps,
        int it, float log_mu) {
    int tid = threadIdx.x;
    if (it > 0) {
        if (flag[it - 1] != 0.f || err[it - 1] < 0.1f) {
            if (blockIdx.x == 0 && tid == 0) flag[it] = 1.f;
            return;
        }
    }
    int r0 = blockIdx.x * 4;
    int w = tid >> 6;

    // v*K2 for my 8 cols
    float4 va = *(const float4*)(v + 4 * tid);
    float4 vb = *(const float4*)(v + 1024 + 4 * tid);
    float vK[8] = { va.x * K2, va.y * K2, va.z * K2, va.w * K2,
                    vb.x * K2, vb.y * K2, vb.z * K2, vb.w * K2 };

    // C tile 4x8 in regs: a[r][g] = (v_j - C_ij)*K2
    float a[4][8];
#pragma unroll
    for (int r = 0; r < 4; ++r) {
        const float* row = Cws + (size_t)(r0 + r) * NN;
        float4 ca = *(const float4*)(row + 4 * tid);
        float4 cb = *(const float4*)(row + 1024 + 4 * tid);
        a[r][0] = fmaf(-K2, ca.x, vK[0]); a[r][1] = fmaf(-K2, ca.y, vK[1]);
        a[r][2] = fmaf(-K2, ca.z, vK[2]); a[r][3] = fmaf(-K2, ca.w, vK[3]);
        a[r][4] = fmaf(-K2, cb.x, vK[4]); a[r][5] = fmaf(-K2, cb.y, vK[5]);
        a[r][6] = fmaf(-K2, cb.z, vK[6]); a[r][7] = fmaf(-K2, cb.w, vK[7]);
    }

    // ---- row phase: block max per row ----
    float m4[4];
#pragma unroll
    for (int r = 0; r < 4; ++r) {
        float q0 = fmaxf(fmaxf(a[r][0], a[r][1]), fmaxf(a[r][2], a[r][3]));
        float q1 = fmaxf(fmaxf(a[r][4], a[r][5]), fmaxf(a[r][6], a[r][7]));
        m4[r] = fmaxf(q0, q1);
    }
#pragma unroll
    for (int off = 1; off < 64; off <<= 1)
#pragma unroll
        for (int r = 0; r < 4; ++r)
            m4[r] = fmaxf(m4[r], __shfl_xor(m4[r], off));
    __shared__ float wsm[4][4], wss[4][4], uK_lds[4];
    if ((tid & 63) == 0)
#pragma unroll
        for (int r = 0; r < 4; ++r) wsm[w][r] = m4[r];
    __syncthreads();
    float M4[4];
#pragma unroll
    for (int r = 0; r < 4; ++r)
        M4[r] = fmaxf(fmaxf(wsm[0][r], wsm[1][r]), fmaxf(wsm[2][r], wsm[3][r]));

    // ---- row phase: sums ----
    float s4[4];
#pragma unroll
    for (int r = 0; r < 4; ++r) {
        float t0 = fexp2(a[r][0] - M4[r]) + fexp2(a[r][1] - M4[r]);
        float t1 = fexp2(a[r][2] - M4[r]) + fexp2(a[r][3] - M4[r]);
        float t2 = fexp2(a[r][4] - M4[r]) + fexp2(a[r][5] - M4[r]);
        float t3 = fexp2(a[r][6] - M4[r]) + fexp2(a[r][7] - M4[r]);
        s4[r] = (t0 + t1) + (t2 + t3);
    }
#pragma unroll
    for (int off = 1; off < 64; off <<= 1)
#pragma unroll
        for (int r = 0; r < 4; ++r)
            s4[r] += __shfl_xor(s4[r], off);
    if ((tid & 63) == 0)
#pragma unroll
        for (int r = 0; r < 4; ++r) wss[w][r] = s4[r];
    __syncthreads();
    if (tid < 4) {
        float S = (wss[0][tid] + wss[1][tid]) + (wss[2][tid] + wss[3][tid]);
        float un = EPSF * (log_mu - LN2F * (M4[tid] + flog2(S)));
        du[r0 + tid] = fabsf(un - u[r0 + tid]);
        u[r0 + tid] = un;
        uK_lds[tid] = un * K2;
    }
    if (blockIdx.x == 0 && tid == 0) flag[it] = 0.f;
    __syncthreads();
    float uKr[4] = { uK_lds[0], uK_lds[1], uK_lds[2], uK_lds[3] };

    // ---- col phase: partial LSE over this block's 4 rows ----
    float cm[8], cs[8];
#pragma unroll
    for (int g = 0; g < 8; ++g) {
        float b0 = a[0][g] + (uKr[0] - vK[g]);
        float b1 = a[1][g] + (uKr[1] - vK[g]);
        float b2 = a[2][g] + (uKr[2] - vK[g]);
        float b3 = a[3][g] + (uKr[3] - vK[g]);
        float m = fmaxf(fmaxf(b0, b1), fmaxf(b2, b3));
        cm[g] = m;
        cs[g] = (fexp2(b0 - m) + fexp2(b1 - m)) + (fexp2(b2 - m) + fexp2(b3 - m));
    }
    size_t base = (size_t)blockIdx.x * NN;
    *(float4*)(pm + base + 4 * tid)        = make_float4(cm[0], cm[1], cm[2], cm[3]);
    *(float4*)(pm + base + 1024 + 4 * tid) = make_float4(cm[4], cm[5], cm[6], cm[7]);
    *(float4*)(ps + base + 4 * tid)        = make_float4(cs[0], cs[1], cs[2], cs[3]);
    *(float4*)(ps + base + 1024 + 4 * tid) = make_float4(cs[4], cs[5], cs[6], cs[7]);
}

// ---------------------------------------------------------------------------
// Kernel 3 (per iter): finish col LSE -> v_j (coalesced panel reads);
// block 0 reduces du -> err[it]. grid 32, block 256.
// Block owns 64 consecutive cols (lane = col). Wave w reads panels w+4k,
// 4 independent LSE streams to shorten the dependent chain.
// ---------------------------------------------------------------------------
__global__ __launch_bounds__(256) void sink_fin(
        const float* __restrict__ pm, const float* __restrict__ ps,
        float* __restrict__ v, const float* __restrict__ du,
        float* __restrict__ err, const float* __restrict__ flag,
        int it, float log_nu) {
    if (flag[it] != 0.f) return;
    int tid = threadIdx.x;
    int w = tid >> 6, l = tid & 63;
    int j = blockIdx.x * 64 + l;

    float M0 = -INFINITY, S0 = 0.f, M1 = -INFINITY, S1 = 0.f;
    float M2 = -INFINITY, S2 = 0.f, M3 = -INFINITY, S3 = 0.f;
#pragma unroll 8
    for (int k = 0; k < 128; k += 4) {
        size_t p0 = (size_t)(w + 4 * k) * NN + j;
        size_t p1 = (size_t)(w + 4 * (k + 1)) * NN + j;
        size_t p2 = (size_t)(w + 4 * (k + 2)) * NN + j;
        size_t p3 = (size_t)(w + 4 * (k + 3)) * NN + j;
        lse_combine(M0, S0, pm[p0], ps[p0]);
        lse_combine(M1, S1, pm[p1], ps[p1]);
        lse_combine(M2, S2, pm[p2], ps[p2]);
        lse_combine(M3, S3, pm[p3], ps[p3]);
    }
    lse_combine(M0, S0, M1, S1);
    lse_combine(M2, S2, M3, S3);
    lse_combine(M0, S0, M2, S2);

    __shared__ float lsm[4][64], lss[4][64];
    lsm[w][l] = M0; lss[w][l] = S0;
    __syncthreads();
    if (tid < 64) {
        float M = lsm[0][tid], S = lss[0][tid];
        lse_combine(M, S, lsm[1][tid], lss[1][tid]);
        lse_combine(M, S, lsm[2][tid], lss[2][tid]);
        lse_combine(M, S, lsm[3][tid], lss[3][tid]);
        v[blockIdx.x * 64 + tid] = EPSF * (log_nu - LN2F * (M + flog2(S)));
    }

    if (blockIdx.x == 0) {
        float t = 0.f;
        for (int k = tid; k < NN; k += 256) t += du[k];
#pragma unroll
        for (int off = 1; off < 64; off <<= 1) t += __shfl_xor(t, off);
        __shared__ float sl[4];
        if ((tid & 63) == 0) sl[tid >> 6] = t;
        __syncthreads();
        if (tid == 0) err[it] = sl[0] + sl[1] + sl[2] + sl[3];
    }
}

// ---------------------------------------------------------------------------
// Kernel 4: pi = exp((-C+u+v)/eps), cost = sum(pi*C)
// grid 256 (8 rows per block), block 256. One atomic per block.
// ---------------------------------------------------------------------------
__global__ __launch_bounds__(256) void sink_pi(
        const float* __restrict__ Cws, const float* __restrict__ u,
        const float* __restrict__ v, float* __restrict__ pi,
        float* __restrict__ cost) {
    int tid = threadIdx.x;
    const float4* v4 = (const float4*)v;
    float local = 0.f;
    for (int rr = 0; rr < 8; ++rr) {
        int i = blockIdx.x * 8 + rr;
        float ui = u[i];
        const float4* row4 = (const float4*)(Cws + (size_t)i * NN);
        float* prow = pi + (size_t)i * NN;
        for (int k = tid; k < NN / 4; k += 256) {
            float4 c = row4[k];
            float4 vv = v4[k];
            float p0 = fexp2((ui + vv.x - c.x) * K2);
            float p1 = fexp2((ui + vv.y - c.y) * K2);
            float p2 = fexp2((ui + vv.z - c.z) * K2);
            float p3 = fexp2((ui + vv.w - c.w) * K2);
            prow[4 * k + 0] = p0;
            prow[4 * k + 1] = p1;
            prow[4 * k + 2] = p2;
            prow[4 * k + 3] = p3;
            local = fmaf(p0, c.x, local);
            local = fmaf(p1, c.y, local);
            local = fmaf(p2, c.z, local);
            local = fmaf(p3, c.w, local);
        }
    }
#pragma unroll
    for (int off = 1; off < 64; off <<= 1) local += __shfl_xor(local, off);
    __shared__ float sl[4];
    if ((tid & 63) == 0) sl[tid >> 6] = local;
    __syncthreads();
    if (tid == 0) atomicAdd(cost, sl[0] + sl[1] + sl[2] + sl[3]);
}

extern "C" void kernel_launch(void* const* d_in, const int* in_sizes, int n_in,
                              void* d_out, int out_size, void* d_ws, size_t ws_size,
                              hipStream_t stream) {
    const float* x = (const float*)d_in[0];
    const float* y = (const float*)d_in[1];
    float* out  = (float*)d_out;
    float* cost = out;                       // [0]
    float* pi   = out + 1;                   // [1 .. 1+2048*2048)
    float* Cout = out + 1 + (size_t)NN * NN; // [.. 1+2*2048*2048)

    float* ws   = (float*)d_ws;
    float* u    = ws + U_OFF;
    float* v    = ws + V_OFF;
    float* err  = ws + ERR_OFF;
    float* flag = ws + FLG_OFF;
    float* du   = ws + DU_OFF;
    float* Cws  = ws + CWS_OFF;
    float* pm   = ws + PM_OFF;
    float* ps   = ws + PS_OFF;

    float log_mu = (float)log(1.0 / 2048.0 + 1e-8); // n == m -> log_nu == log_mu

    sink_cost_matrix<<<dim3(32, 16), 256, 0, stream>>>(x, y, Cout, Cws, ws, cost);
    for (int it = 0; it < 10; ++it) {
        sink_iter<<<512, 256, 0, stream>>>(Cws, u, v, du, err, flag, pm, ps, it, log_mu);
        sink_fin<<<32, 256, 0, stream>>>(pm, ps, v, du, err, flag, it, log_mu);
    }
    sink_pi<<<256, 256, 0, stream>>>(Cws, u, v, pi, cost);
}

// Round 7
// 190.484 us; speedup vs baseline: 4.0858x; 2.3950x over previous
//
#include <hip/hip_runtime.h>
#include <cmath>

#define NN 2048

#define EPSF 0.1f
#define K2 14.426950408889634f   /* (1/eps) * log2(e) */
#define LN2F 0.6931471805599453f

// ws layout (floats)
#define U_OFF   0
#define V_OFF   2048
#define ERR_OFF 4096
#define FLG_OFF 4112
#define DU_OFF  4128
#define CWS_OFF 6176
#define PM_OFF  (6176 + 2048*2048)
#define PS_OFF  (PM_OFF + 256*2048)

__device__ __forceinline__ float fexp2(float x) { return __builtin_amdgcn_exp2f(x); }
__device__ __forceinline__ float flog2(float x) { return __builtin_amdgcn_logf(x); }

// online logsumexp combine in base-2 domain: (M,S) <- (M,S) ++ (m,s)
__device__ __forceinline__ void lse_combine(float& M, float& S, float m, float s) {
    float mn = fmaxf(M, m);
    S = S * fexp2(M - mn) + s * fexp2(m - mn);
    M = mn;
}

// ---------------------------------------------------------------------------
// Kernel 1: C[i][j] = sum_d (x[i][d]-y[j][d])^2 -> Cout (output) + Cws (aligned)
// Also zero-inits u/v/err/flag/du and cost. grid (32, 16), block 256.
// ---------------------------------------------------------------------------
__global__ __launch_bounds__(256) void sink_cost_matrix(
        const float* __restrict__ x, const float* __restrict__ y,
        float* __restrict__ Cout, float* __restrict__ Cws,
        float* __restrict__ wsz, float* __restrict__ cost) {
    __shared__ float xs[128][65];
    __shared__ float ys[64][65];
    int tid = threadIdx.x;
    int bj = blockIdx.x, bi = blockIdx.y;

    if (bi == 0 && bj == 0) {
        // u(2048)+v(2048)+err(16)+flag(16)+du(2048) = 6176
        for (int k = tid; k < 6176; k += 256) wsz[k] = 0.f;
        if (tid == 0) cost[0] = 0.f;
    }

    const float4* x4 = (const float4*)x;
    const float4* y4 = (const float4*)y;
    for (int q = tid; q < 128 * 16; q += 256) {
        int r = q >> 4, dq = q & 15;
        float4 val = x4[(size_t)(bi * 128 + r) * 16 + dq];
        xs[r][dq * 4 + 0] = val.x; xs[r][dq * 4 + 1] = val.y;
        xs[r][dq * 4 + 2] = val.z; xs[r][dq * 4 + 3] = val.w;
    }
    for (int q = tid; q < 64 * 16; q += 256) {
        int r = q >> 4, dq = q & 15;
        float4 val = y4[(size_t)(bj * 64 + r) * 16 + dq];
        ys[r][dq * 4 + 0] = val.x; ys[r][dq * 4 + 1] = val.y;
        ys[r][dq * 4 + 2] = val.z; ys[r][dq * 4 + 3] = val.w;
    }
    __syncthreads();

    int tx = tid & 15, ty = tid >> 4;
    float acc[8][4];
#pragma unroll
    for (int ii = 0; ii < 8; ++ii)
#pragma unroll
        for (int jj = 0; jj < 4; ++jj) acc[ii][jj] = 0.f;

#pragma unroll 4
    for (int dd = 0; dd < 64; ++dd) {
        float xv[8], yv[4];
#pragma unroll
        for (int ii = 0; ii < 8; ++ii) xv[ii] = xs[ty + 16 * ii][dd];
#pragma unroll
        for (int jj = 0; jj < 4; ++jj) yv[jj] = ys[tx + 16 * jj][dd];
#pragma unroll
        for (int ii = 0; ii < 8; ++ii)
#pragma unroll
            for (int jj = 0; jj < 4; ++jj) {
                float d = xv[ii] - yv[jj];
                acc[ii][jj] = fmaf(d, d, acc[ii][jj]);
            }
    }

#pragma unroll
    for (int ii = 0; ii < 8; ++ii)
#pragma unroll
        for (int jj = 0; jj < 4; ++jj) {
            int gi = bi * 128 + ty + 16 * ii;
            int gj = bj * 64 + tx + 16 * jj;
            Cout[(size_t)gi * NN + gj] = acc[ii][jj];
            Cws [(size_t)gi * NN + gj] = acc[ii][jj];
        }
}

// ---------------------------------------------------------------------------
// Kernel 2 (per iter): ONE pass over C. grid 256, block 512 (2 waves/SIMD).
// Block b owns rows [8b, 8b+8). Thread t owns cols 4t..4t+3.
// Row phase: u_i update + du. Col phase: per-block col partials (m,s),
// panel-major pm/ps[b*2048 + j] (256 panels).
// Gate: flag[it-1] || err[it-1] < 0.1 -> publish flag[it], skip.
// ---------------------------------------------------------------------------
__global__ __launch_bounds__(512) void sink_iter(
        const float* __restrict__ Cws, float* __restrict__ u,
        const float* __restrict__ v, float* __restrict__ du,
        const float* __restrict__ err, float* __restrict__ flag,
        float* __restrict__ pm, float* __restrict__ ps,
        int it, float log_mu) {
    int tid = threadIdx.x;
    if (it > 0) {
        if (flag[it - 1] != 0.f || err[it - 1] < 0.1f) {
            if (blockIdx.x == 0 && tid == 0) flag[it] = 1.f;
            return;
        }
    }
    int r0 = blockIdx.x * 8;
    int w = tid >> 6, l = tid & 63;

    // v*K2 for my 4 cols
    float4 vv = *(const float4*)(v + 4 * tid);
    float vK[4] = { vv.x * K2, vv.y * K2, vv.z * K2, vv.w * K2 };

    // C tile 8x4 in regs: a[r][c] = (v_j - C_ij)*K2
    float a[8][4];
#pragma unroll
    for (int r = 0; r < 8; ++r) {
        float4 ca = *(const float4*)(Cws + (size_t)(r0 + r) * NN + 4 * tid);
        a[r][0] = fmaf(-K2, ca.x, vK[0]);
        a[r][1] = fmaf(-K2, ca.y, vK[1]);
        a[r][2] = fmaf(-K2, ca.z, vK[2]);
        a[r][3] = fmaf(-K2, ca.w, vK[3]);
    }

    // ---- row phase: block max per row ----
    float m8[8];
#pragma unroll
    for (int r = 0; r < 8; ++r)
        m8[r] = fmaxf(fmaxf(a[r][0], a[r][1]), fmaxf(a[r][2], a[r][3]));
#pragma unroll
    for (int off = 1; off < 64; off <<= 1)
#pragma unroll
        for (int r = 0; r < 8; ++r)
            m8[r] = fmaxf(m8[r], __shfl_xor(m8[r], off));
    __shared__ float wsm[8][8], wss[8][8], uK_lds[8];
    if (l == 0)
#pragma unroll
        for (int r = 0; r < 8; ++r) wsm[w][r] = m8[r];
    __syncthreads();
    float M8[8];
#pragma unroll
    for (int r = 0; r < 8; ++r) {
        float q0 = fmaxf(wsm[0][r], wsm[1][r]);
        float q1 = fmaxf(wsm[2][r], wsm[3][r]);
        float q2 = fmaxf(wsm[4][r], wsm[5][r]);
        float q3 = fmaxf(wsm[6][r], wsm[7][r]);
        M8[r] = fmaxf(fmaxf(q0, q1), fmaxf(q2, q3));
    }

    // ---- row phase: sums ----
    float s8[8];
#pragma unroll
    for (int r = 0; r < 8; ++r) {
        float t0 = fexp2(a[r][0] - M8[r]) + fexp2(a[r][1] - M8[r]);
        float t1 = fexp2(a[r][2] - M8[r]) + fexp2(a[r][3] - M8[r]);
        s8[r] = t0 + t1;
    }
#pragma unroll
    for (int off = 1; off < 64; off <<= 1)
#pragma unroll
        for (int r = 0; r < 8; ++r)
            s8[r] += __shfl_xor(s8[r], off);
    if (l == 0)
#pragma unroll
        for (int r = 0; r < 8; ++r) wss[w][r] = s8[r];
    __syncthreads();
    if (tid < 8) {
        float S = ((wss[0][tid] + wss[1][tid]) + (wss[2][tid] + wss[3][tid]))
                + ((wss[4][tid] + wss[5][tid]) + (wss[6][tid] + wss[7][tid]));
        float un = EPSF * (log_mu - LN2F * (M8[tid] + flog2(S)));
        du[r0 + tid] = fabsf(un - u[r0 + tid]);
        u[r0 + tid] = un;
        uK_lds[tid] = un * K2;
    }
    if (blockIdx.x == 0 && tid == 0) flag[it] = 0.f;
    __syncthreads();
    float uKr[8];
#pragma unroll
    for (int r = 0; r < 8; ++r) uKr[r] = uK_lds[r];

    // ---- col phase: partial LSE over this block's 8 rows ----
    float cm[4], cs[4];
#pragma unroll
    for (int c = 0; c < 4; ++c) {
        float b0 = a[0][c] + (uKr[0] - vK[c]);
        float b1 = a[1][c] + (uKr[1] - vK[c]);
        float b2 = a[2][c] + (uKr[2] - vK[c]);
        float b3 = a[3][c] + (uKr[3] - vK[c]);
        float b4 = a[4][c] + (uKr[4] - vK[c]);
        float b5 = a[5][c] + (uKr[5] - vK[c]);
        float b6 = a[6][c] + (uKr[6] - vK[c]);
        float b7 = a[7][c] + (uKr[7] - vK[c]);
        float m = fmaxf(fmaxf(fmaxf(b0, b1), fmaxf(b2, b3)),
                        fmaxf(fmaxf(b4, b5), fmaxf(b6, b7)));
        cm[c] = m;
        cs[c] = (fexp2(b0 - m) + fexp2(b1 - m)) + (fexp2(b2 - m) + fexp2(b3 - m))
              + (fexp2(b4 - m) + fexp2(b5 - m)) + (fexp2(b6 - m) + fexp2(b7 - m));
    }
    size_t base = (size_t)blockIdx.x * NN + 4 * tid;
    *(float4*)(pm + base) = make_float4(cm[0], cm[1], cm[2], cm[3]);
    *(float4*)(ps + base) = make_float4(cs[0], cs[1], cs[2], cs[3]);
}

// ---------------------------------------------------------------------------
// Kernel 3 (per iter): finish column LSE -> v_j; block 0 reduces du -> err[it].
// grid 128, block 256: 16 cols/block, 16 threads/col, 16 panels each.
// ---------------------------------------------------------------------------
__global__ __launch_bounds__(256) void sink_fin(
        const float* __restrict__ pm, const float* __restrict__ ps,
        float* __restrict__ v, const float* __restrict__ du,
        float* __restrict__ err, const float* __restrict__ flag,
        int it, float log_nu) {
    if (flag[it] != 0.f) return;
    int tid = threadIdx.x;
    int c = tid >> 4, l = tid & 15;
    int j = blockIdx.x * 16 + c;

    float M0 = -INFINITY, S0 = 0.f, M1 = -INFINITY, S1 = 0.f;
#pragma unroll
    for (int k = 0; k < 8; ++k) {
        int p0 = l * 16 + 2 * k, p1 = p0 + 1;
        lse_combine(M0, S0, pm[(size_t)p0 * NN + j], ps[(size_t)p0 * NN + j]);
        lse_combine(M1, S1, pm[(size_t)p1 * NN + j], ps[(size_t)p1 * NN + j]);
    }
    lse_combine(M0, S0, M1, S1);
#pragma unroll
    for (int off = 1; off < 16; off <<= 1) {
        float mo = __shfl_xor(M0, off);
        float so = __shfl_xor(S0, off);
        lse_combine(M0, S0, mo, so);
    }
    if (l == 0) v[j] = EPSF * (log_nu - LN2F * (M0 + flog2(S0)));

    if (blockIdx.x == 0) {
        float t = 0.f;
        for (int k = tid; k < NN; k += 256) t += du[k];
#pragma unroll
        for (int off = 1; off < 64; off <<= 1) t += __shfl_xor(t, off);
        __shared__ float sl[4];
        if ((tid & 63) == 0) sl[tid >> 6] = t;
        __syncthreads();
        if (tid == 0) err[it] = sl[0] + sl[1] + sl[2] + sl[3];
    }
}

// ---------------------------------------------------------------------------
// Kernel 4: pi = exp((-C+u+v)/eps), cost = sum(pi*C)
// grid 256 (8 rows per block), block 256. One atomic per block.
// ---------------------------------------------------------------------------
__global__ __launch_bounds__(256) void sink_pi(
        const float* __restrict__ Cws, const float* __restrict__ u,
        const float* __restrict__ v, float* __restrict__ pi,
        float* __restrict__ cost) {
    int tid = threadIdx.x;
    const float4* v4 = (const float4*)v;
    float local = 0.f;
    for (int rr = 0; rr < 8; ++rr) {
        int i = blockIdx.x * 8 + rr;
        float ui = u[i];
        const float4* row4 = (const float4*)(Cws + (size_t)i * NN);
        float* prow = pi + (size_t)i * NN;
        for (int k = tid; k < NN / 4; k += 256) {
            float4 c = row4[k];
            float4 vv = v4[k];
            float p0 = fexp2((ui + vv.x - c.x) * K2);
            float p1 = fexp2((ui + vv.y - c.y) * K2);
            float p2 = fexp2((ui + vv.z - c.z) * K2);
            float p3 = fexp2((ui + vv.w - c.w) * K2);
            prow[4 * k + 0] = p0;
            prow[4 * k + 1] = p1;
            prow[4 * k + 2] = p2;
            prow[4 * k + 3] = p3;
            local = fmaf(p0, c.x, local);
            local = fmaf(p1, c.y, local);
            local = fmaf(p2, c.z, local);
            local = fmaf(p3, c.w, local);
        }
    }
#pragma unroll
    for (int off = 1; off < 64; off <<= 1) local += __shfl_xor(local, off);
    __shared__ float sl[4];
    if ((tid & 63) == 0) sl[tid >> 6] = local;
    __syncthreads();
    if (tid == 0) atomicAdd(cost, sl[0] + sl[1] + sl[2] + sl[3]);
}

extern "C" void kernel_launch(void* const* d_in, const int* in_sizes, int n_in,
                              void* d_out, int out_size, void* d_ws, size_t ws_size,
                              hipStream_t stream) {
    const float* x = (const float*)d_in[0];
    const float* y = (const float*)d_in[1];
    float* out  = (float*)d_out;
    float* cost = out;                       // [0]
    float* pi   = out + 1;                   // [1 .. 1+2048*2048)
    float* Cout = out + 1 + (size_t)NN * NN; // [.. 1+2*2048*2048)

    float* ws   = (float*)d_ws;
    float* u    = ws + U_OFF;
    float* v    = ws + V_OFF;
    float* err  = ws + ERR_OFF;
    float* flag = ws + FLG_OFF;
    float* du   = ws + DU_OFF;
    float* Cws  = ws + CWS_OFF;
    float* pm   = ws + PM_OFF;
    float* ps   = ws + PS_OFF;

    float log_mu = (float)log(1.0 / 2048.0 + 1e-8); // n == m -> log_nu == log_mu

    sink_cost_matrix<<<dim3(32, 16), 256, 0, stream>>>(x, y, Cout, Cws, ws, cost);
    for (int it = 0; it < 10; ++it) {
        sink_iter<<<256, 512, 0, stream>>>(Cws, u, v, du, err, flag, pm, ps, it, log_mu);
        sink_fin<<<128, 256, 0, stream>>>(pm, ps, v, du, err, flag, it, log_mu);
    }
    sink_pi<<<256, 256, 0, stream>>>(Cws, u, v, pi, cost);
}

// Round 8
// 177.650 us; speedup vs baseline: 4.3810x; 1.0722x over previous
//
#include <hip/hip_runtime.h>
#include <cmath>

#define NN 2048

#define EPSF 0.1f
#define K2 14.426950408889634f   /* (1/eps) * log2(e) */
#define LN2F 0.6931471805599453f

// ws layout (floats)
#define U_OFF   0
#define V_OFF   2048
#define ERR_OFF 4096
#define FLG_OFF 4112
#define DU_OFF  4128
#define CT_OFF  6176              // 2048*2048 transposed cost matrix

__device__ __forceinline__ float fexp2(float x) { return __builtin_amdgcn_exp2f(x); }
__device__ __forceinline__ float flog2(float x) { return __builtin_amdgcn_logf(x); }

// ---------------------------------------------------------------------------
// Kernel 1 (x2): dst[gi][gj] = sum_d (a[gi][d]-b[gj][d])^2, row-major dst.
// Launched once as (x,y)->Cout and once as (y,x)->CT.
// do_init: zero u/v/err/flag/du + cost.  grid (32,16), block 256.
// ---------------------------------------------------------------------------
__global__ __launch_bounds__(256) void sink_cost(
        const float* __restrict__ a, const float* __restrict__ b,
        float* __restrict__ dst, float* __restrict__ wsz,
        float* __restrict__ cost, int do_init) {
    __shared__ float xs[128][65];
    __shared__ float ys[64][65];
    int tid = threadIdx.x;
    int bj = blockIdx.x, bi = blockIdx.y;

    if (do_init && bi == 0 && bj == 0) {
        // u(2048)+v(2048)+err(16)+flag(16)+du(2048) = 6176
        for (int k = tid; k < 6176; k += 256) wsz[k] = 0.f;
        if (tid == 0) cost[0] = 0.f;
    }

    const float4* a4 = (const float4*)a;
    const float4* b4 = (const float4*)b;
    for (int q = tid; q < 128 * 16; q += 256) {
        int r = q >> 4, dq = q & 15;
        float4 val = a4[(size_t)(bi * 128 + r) * 16 + dq];
        xs[r][dq * 4 + 0] = val.x; xs[r][dq * 4 + 1] = val.y;
        xs[r][dq * 4 + 2] = val.z; xs[r][dq * 4 + 3] = val.w;
    }
    for (int q = tid; q < 64 * 16; q += 256) {
        int r = q >> 4, dq = q & 15;
        float4 val = b4[(size_t)(bj * 64 + r) * 16 + dq];
        ys[r][dq * 4 + 0] = val.x; ys[r][dq * 4 + 1] = val.y;
        ys[r][dq * 4 + 2] = val.z; ys[r][dq * 4 + 3] = val.w;
    }
    __syncthreads();

    int tx = tid & 15, ty = tid >> 4;
    float acc[8][4];
#pragma unroll
    for (int ii = 0; ii < 8; ++ii)
#pragma unroll
        for (int jj = 0; jj < 4; ++jj) acc[ii][jj] = 0.f;

#pragma unroll 4
    for (int dd = 0; dd < 64; ++dd) {
        float xv[8], yv[4];
#pragma unroll
        for (int ii = 0; ii < 8; ++ii) xv[ii] = xs[ty + 16 * ii][dd];
#pragma unroll
        for (int jj = 0; jj < 4; ++jj) yv[jj] = ys[tx + 16 * jj][dd];
#pragma unroll
        for (int ii = 0; ii < 8; ++ii)
#pragma unroll
            for (int jj = 0; jj < 4; ++jj) {
                float d = xv[ii] - yv[jj];
                acc[ii][jj] = fmaf(d, d, acc[ii][jj]);
            }
    }

#pragma unroll
    for (int ii = 0; ii < 8; ++ii)
#pragma unroll
        for (int jj = 0; jj < 4; ++jj) {
            int gi = bi * 128 + ty + 16 * ii;
            int gj = bj * 64 + tx + 16 * jj;
            dst[(size_t)gi * NN + gj] = acc[ii][jj];
        }
}

// ---------------------------------------------------------------------------
// Kernel 2 (per iter, u half): u_i = eps*(log_mu - LSE_j((v_j - C_ij)/eps)).
// grid 256, block 512. Block b: rows [8b,8b+8) of C (row-major in d_out,
// 4B-misaligned -> scalar dword loads). Writes u, du; publishes flag[it].
// ---------------------------------------------------------------------------
__global__ __launch_bounds__(512) void sink_u(
        const float* __restrict__ C, float* __restrict__ u,
        const float* __restrict__ v, float* __restrict__ du,
        const float* __restrict__ err, float* __restrict__ flag,
        int it, float log_mu) {
    int tid = threadIdx.x;
    if (it > 0) {
        if (flag[it - 1] != 0.f || err[it - 1] < 0.1f) {
            if (blockIdx.x == 0 && tid == 0) flag[it] = 1.f;
            return;
        }
    }
    int r0 = blockIdx.x * 8;
    int w = tid >> 6, l = tid & 63;

    float4 vv = *(const float4*)(v + 4 * tid);
    float vK[4] = { vv.x * K2, vv.y * K2, vv.z * K2, vv.w * K2 };

    float a[8][4];
#pragma unroll
    for (int r = 0; r < 8; ++r) {
        const float* row = C + (size_t)(r0 + r) * NN + 4 * tid;
        a[r][0] = fmaf(-K2, row[0], vK[0]);
        a[r][1] = fmaf(-K2, row[1], vK[1]);
        a[r][2] = fmaf(-K2, row[2], vK[2]);
        a[r][3] = fmaf(-K2, row[3], vK[3]);
    }

    // block max per row
    float m8[8];
#pragma unroll
    for (int r = 0; r < 8; ++r)
        m8[r] = fmaxf(fmaxf(a[r][0], a[r][1]), fmaxf(a[r][2], a[r][3]));
#pragma unroll
    for (int off = 1; off < 64; off <<= 1)
#pragma unroll
        for (int r = 0; r < 8; ++r)
            m8[r] = fmaxf(m8[r], __shfl_xor(m8[r], off));
    __shared__ float wsm[8][8], wss[8][8];
    if (l == 0)
#pragma unroll
        for (int r = 0; r < 8; ++r) wsm[w][r] = m8[r];
    __syncthreads();
    float M8[8];
#pragma unroll
    for (int r = 0; r < 8; ++r) {
        float q0 = fmaxf(wsm[0][r], wsm[1][r]);
        float q1 = fmaxf(wsm[2][r], wsm[3][r]);
        float q2 = fmaxf(wsm[4][r], wsm[5][r]);
        float q3 = fmaxf(wsm[6][r], wsm[7][r]);
        M8[r] = fmaxf(fmaxf(q0, q1), fmaxf(q2, q3));
    }

    // block sum per row
    float s8[8];
#pragma unroll
    for (int r = 0; r < 8; ++r) {
        float t0 = fexp2(a[r][0] - M8[r]) + fexp2(a[r][1] - M8[r]);
        float t1 = fexp2(a[r][2] - M8[r]) + fexp2(a[r][3] - M8[r]);
        s8[r] = t0 + t1;
    }
#pragma unroll
    for (int off = 1; off < 64; off <<= 1)
#pragma unroll
        for (int r = 0; r < 8; ++r)
            s8[r] += __shfl_xor(s8[r], off);
    if (l == 0)
#pragma unroll
        for (int r = 0; r < 8; ++r) wss[w][r] = s8[r];
    __syncthreads();
    if (tid < 8) {
        float S = ((wss[0][tid] + wss[1][tid]) + (wss[2][tid] + wss[3][tid]))
                + ((wss[4][tid] + wss[5][tid]) + (wss[6][tid] + wss[7][tid]));
        float un = EPSF * (log_mu - LN2F * (M8[tid] + flog2(S)));
        du[r0 + tid] = fabsf(un - u[r0 + tid]);
        u[r0 + tid] = un;
    }
    if (blockIdx.x == 0 && tid == 0) flag[it] = 0.f;
}

// ---------------------------------------------------------------------------
// Kernel 3 (per iter, v half): v_j = eps*(log_nu - LSE_i((u_i - C_ij)/eps)).
// Identical shape on CT (aligned, in ws). Block 0 reduces du -> err[it].
// ---------------------------------------------------------------------------
__global__ __launch_bounds__(512) void sink_v(
        const float* __restrict__ CT, float* __restrict__ v,
        const float* __restrict__ u, const float* __restrict__ du,
        float* __restrict__ err, const float* __restrict__ flag,
        int it, float log_nu) {
    if (flag[it] != 0.f) return;
    int tid = threadIdx.x;
    int j0 = blockIdx.x * 8;
    int w = tid >> 6, l = tid & 63;

    float4 uu = *(const float4*)(u + 4 * tid);
    float uK[4] = { uu.x * K2, uu.y * K2, uu.z * K2, uu.w * K2 };

    float a[8][4];
#pragma unroll
    for (int r = 0; r < 8; ++r) {
        float4 ct = *(const float4*)(CT + (size_t)(j0 + r) * NN + 4 * tid);
        a[r][0] = fmaf(-K2, ct.x, uK[0]);
        a[r][1] = fmaf(-K2, ct.y, uK[1]);
        a[r][2] = fmaf(-K2, ct.z, uK[2]);
        a[r][3] = fmaf(-K2, ct.w, uK[3]);
    }

    float m8[8];
#pragma unroll
    for (int r = 0; r < 8; ++r)
        m8[r] = fmaxf(fmaxf(a[r][0], a[r][1]), fmaxf(a[r][2], a[r][3]));
#pragma unroll
    for (int off = 1; off < 64; off <<= 1)
#pragma unroll
        for (int r = 0; r < 8; ++r)
            m8[r] = fmaxf(m8[r], __shfl_xor(m8[r], off));
    __shared__ float wsm[8][8], wss[8][8];
    if (l == 0)
#pragma unroll
        for (int r = 0; r < 8; ++r) wsm[w][r] = m8[r];
    __syncthreads();
    float M8[8];
#pragma unroll
    for (int r = 0; r < 8; ++r) {
        float q0 = fmaxf(wsm[0][r], wsm[1][r]);
        float q1 = fmaxf(wsm[2][r], wsm[3][r]);
        float q2 = fmaxf(wsm[4][r], wsm[5][r]);
        float q3 = fmaxf(wsm[6][r], wsm[7][r]);
        M8[r] = fmaxf(fmaxf(q0, q1), fmaxf(q2, q3));
    }

    float s8[8];
#pragma unroll
    for (int r = 0; r < 8; ++r) {
        float t0 = fexp2(a[r][0] - M8[r]) + fexp2(a[r][1] - M8[r]);
        float t1 = fexp2(a[r][2] - M8[r]) + fexp2(a[r][3] - M8[r]);
        s8[r] = t0 + t1;
    }
#pragma unroll
    for (int off = 1; off < 64; off <<= 1)
#pragma unroll
        for (int r = 0; r < 8; ++r)
            s8[r] += __shfl_xor(s8[r], off);
    if (l == 0)
#pragma unroll
        for (int r = 0; r < 8; ++r) wss[w][r] = s8[r];
    __syncthreads();
    if (tid < 8) {
        float S = ((wss[0][tid] + wss[1][tid]) + (wss[2][tid] + wss[3][tid]))
                + ((wss[4][tid] + wss[5][tid]) + (wss[6][tid] + wss[7][tid]));
        v[j0 + tid] = EPSF * (log_nu - LN2F * (M8[tid] + flog2(S)));
    }

    if (blockIdx.x == 0) {
        float t = ((du[tid] + du[tid + 512]) + (du[tid + 1024] + du[tid + 1536]));
#pragma unroll
        for (int off = 1; off < 64; off <<= 1) t += __shfl_xor(t, off);
        __shared__ float sl[8];
        if (l == 0) sl[w] = t;
        __syncthreads();
        if (tid == 0)
            err[it] = ((sl[0] + sl[1]) + (sl[2] + sl[3]))
                    + ((sl[4] + sl[5]) + (sl[6] + sl[7]));
    }
}

// ---------------------------------------------------------------------------
// Kernel 4: pi = exp((-C+u+v)/eps), cost = sum(pi*C)
// grid 256 (8 rows per block), block 256. Scalar C reads (misaligned region).
// ---------------------------------------------------------------------------
__global__ __launch_bounds__(256) void sink_pi(
        const float* __restrict__ C, const float* __restrict__ u,
        const float* __restrict__ v, float* __restrict__ pi,
        float* __restrict__ cost) {
    int tid = threadIdx.x;
    const float4* v4 = (const float4*)v;
    float local = 0.f;
    for (int rr = 0; rr < 8; ++rr) {
        int i = blockIdx.x * 8 + rr;
        float ui = u[i];
        const float* row = C + (size_t)i * NN;
        float* prow = pi + (size_t)i * NN;
        for (int k = tid; k < NN / 4; k += 256) {
            float c0 = row[4 * k + 0], c1 = row[4 * k + 1];
            float c2 = row[4 * k + 2], c3 = row[4 * k + 3];
            float4 vv = v4[k];
            float p0 = fexp2((ui + vv.x - c0) * K2);
            float p1 = fexp2((ui + vv.y - c1) * K2);
            float p2 = fexp2((ui + vv.z - c2) * K2);
            float p3 = fexp2((ui + vv.w - c3) * K2);
            prow[4 * k + 0] = p0;
            prow[4 * k + 1] = p1;
            prow[4 * k + 2] = p2;
            prow[4 * k + 3] = p3;
            local = fmaf(p0, c0, local);
            local = fmaf(p1, c1, local);
            local = fmaf(p2, c2, local);
            local = fmaf(p3, c3, local);
        }
    }
#pragma unroll
    for (int off = 1; off < 64; off <<= 1) local += __shfl_xor(local, off);
    __shared__ float sl[4];
    if ((tid & 63) == 0) sl[tid >> 6] = local;
    __syncthreads();
    if (tid == 0) atomicAdd(cost, sl[0] + sl[1] + sl[2] + sl[3]);
}

extern "C" void kernel_launch(void* const* d_in, const int* in_sizes, int n_in,
                              void* d_out, int out_size, void* d_ws, size_t ws_size,
                              hipStream_t stream) {
    const float* x = (const float*)d_in[0];
    const float* y = (const float*)d_in[1];
    float* out  = (float*)d_out;
    float* cost = out;                       // [0]
    float* pi   = out + 1;                   // [1 .. 1+2048*2048)
    float* Cout = out + 1 + (size_t)NN * NN; // [.. 1+2*2048*2048)

    float* ws   = (float*)d_ws;
    float* u    = ws + U_OFF;
    float* v    = ws + V_OFF;
    float* err  = ws + ERR_OFF;
    float* flag = ws + FLG_OFF;
    float* du   = ws + DU_OFF;
    float* CT   = ws + CT_OFF;

    float log_mu = (float)log(1.0 / 2048.0 + 1e-8); // n == m -> log_nu == log_mu

    sink_cost<<<dim3(32, 16), 256, 0, stream>>>(x, y, Cout, ws, cost, 1);
    sink_cost<<<dim3(32, 16), 256, 0, stream>>>(y, x, CT, ws, cost, 0);
    for (int it = 0; it < 10; ++it) {
        sink_u<<<256, 512, 0, stream>>>(Cout, u, v, du, err, flag, it, log_mu);
        sink_v<<<256, 512, 0, stream>>>(CT, v, u, du, err, flag, it, log_mu);
    }
    sink_pi<<<256, 256, 0, stream>>>(Cout, u, v, pi, cost);
}

// Round 9
// 162.694 us; speedup vs baseline: 4.7838x; 1.0919x over previous
//
#include <hip/hip_runtime.h>
#include <cmath>

#define NN 2048

#define EPSF 0.1f
#define K2 14.426950408889634f   /* (1/eps) * log2(e) */
#define LN2F 0.6931471805599453f

// ws layout (floats)
#define U_OFF   0
#define V_OFF   2048
#define ERR_OFF 4096
#define FLG_OFF 4112
#define DU_OFF  4128
#define CT_OFF  6176              // 2048*2048 transposed cost matrix

__device__ __forceinline__ float fexp2(float x) { return __builtin_amdgcn_exp2f(x); }
__device__ __forceinline__ float flog2(float x) { return __builtin_amdgcn_logf(x); }

// ---------------------------------------------------------------------------
// Kernel 1: one pass computes the 128x64 distance tile and writes BOTH
// Cout[i][j] (row-major, misaligned d_out region -> scalar stores) and
// CT[j][i] (aligned ws, coalesced float4 stores via LDS transpose through xs).
// Also zero-inits u/v/err/flag/du and cost. grid (32, 16), block 256.
// ---------------------------------------------------------------------------
__global__ __launch_bounds__(256) void sink_cost(
        const float* __restrict__ x, const float* __restrict__ y,
        float* __restrict__ Cout, float* __restrict__ CT,
        float* __restrict__ wsz, float* __restrict__ cost) {
    __shared__ float xs[128][65];
    __shared__ float ys[64][65];
    int tid = threadIdx.x;
    int bj = blockIdx.x, bi = blockIdx.y;

    if (bi == 0 && bj == 0) {
        // u(2048)+v(2048)+err(16)+flag(16)+du(2048) = 6176
        for (int k = tid; k < 6176; k += 256) wsz[k] = 0.f;
        if (tid == 0) cost[0] = 0.f;
    }

    const float4* x4 = (const float4*)x;
    const float4* y4 = (const float4*)y;
    for (int q = tid; q < 128 * 16; q += 256) {
        int r = q >> 4, dq = q & 15;
        float4 val = x4[(size_t)(bi * 128 + r) * 16 + dq];
        xs[r][dq * 4 + 0] = val.x; xs[r][dq * 4 + 1] = val.y;
        xs[r][dq * 4 + 2] = val.z; xs[r][dq * 4 + 3] = val.w;
    }
    for (int q = tid; q < 64 * 16; q += 256) {
        int r = q >> 4, dq = q & 15;
        float4 val = y4[(size_t)(bj * 64 + r) * 16 + dq];
        ys[r][dq * 4 + 0] = val.x; ys[r][dq * 4 + 1] = val.y;
        ys[r][dq * 4 + 2] = val.z; ys[r][dq * 4 + 3] = val.w;
    }
    __syncthreads();

    int tx = tid & 15, ty = tid >> 4;
    float acc[8][4];
#pragma unroll
    for (int ii = 0; ii < 8; ++ii)
#pragma unroll
        for (int jj = 0; jj < 4; ++jj) acc[ii][jj] = 0.f;

#pragma unroll 4
    for (int dd = 0; dd < 64; ++dd) {
        float xv[8], yv[4];
#pragma unroll
        for (int ii = 0; ii < 8; ++ii) xv[ii] = xs[ty + 16 * ii][dd];
#pragma unroll
        for (int jj = 0; jj < 4; ++jj) yv[jj] = ys[tx + 16 * jj][dd];
#pragma unroll
        for (int ii = 0; ii < 8; ++ii)
#pragma unroll
            for (int jj = 0; jj < 4; ++jj) {
                float d = xv[ii] - yv[jj];
                acc[ii][jj] = fmaf(d, d, acc[ii][jj]);
            }
    }

    // C (row-major) stores + stage tile into xs for the transpose
    __syncthreads();   // all compute reads of xs/ys done before overwrite
#pragma unroll
    for (int ii = 0; ii < 8; ++ii)
#pragma unroll
        for (int jj = 0; jj < 4; ++jj) {
            int ri = ty + 16 * ii;          // local row (x index)
            int cj = tx + 16 * jj;          // local col (y index)
            Cout[(size_t)(bi * 128 + ri) * NN + bj * 64 + cj] = acc[ii][jj];
            xs[ri][cj] = acc[ii][jj];
        }
    __syncthreads();

    // CT[j][i]: 64 rows x 128 cols per block; thread: row c = tid>>2,
    // cols rb..rb+31 (rb = (tid&3)*32). 512B contiguous per 4-lane group.
    int c = tid >> 2, rb = (tid & 3) * 32;
    float4* dst = (float4*)(CT + (size_t)(bj * 64 + c) * NN + bi * 128 + rb);
#pragma unroll
    for (int k = 0; k < 8; ++k) {
        dst[k] = make_float4(xs[rb + 4 * k + 0][c], xs[rb + 4 * k + 1][c],
                             xs[rb + 4 * k + 2][c], xs[rb + 4 * k + 3][c]);
    }
}

// ---------------------------------------------------------------------------
// Kernel 2 (per iter, u half): u_i = eps*(log_mu - LSE_j((v_j - C_ij)/eps)).
// grid 256, block 512. Block b: rows [8b,8b+8) of C (row-major in d_out,
// 4B-misaligned -> scalar dword loads). Writes u, du; publishes flag[it].
// ---------------------------------------------------------------------------
__global__ __launch_bounds__(512) void sink_u(
        const float* __restrict__ C, float* __restrict__ u,
        const float* __restrict__ v, float* __restrict__ du,
        const float* __restrict__ err, float* __restrict__ flag,
        int it, float log_mu) {
    int tid = threadIdx.x;
    if (it > 0) {
        if (flag[it - 1] != 0.f || err[it - 1] < 0.1f) {
            if (blockIdx.x == 0 && tid == 0) flag[it] = 1.f;
            return;
        }
    }
    int r0 = blockIdx.x * 8;
    int w = tid >> 6, l = tid & 63;

    float4 vv = *(const float4*)(v + 4 * tid);
    float vK[4] = { vv.x * K2, vv.y * K2, vv.z * K2, vv.w * K2 };

    float a[8][4];
#pragma unroll
    for (int r = 0; r < 8; ++r) {
        const float* row = C + (size_t)(r0 + r) * NN + 4 * tid;
        a[r][0] = fmaf(-K2, row[0], vK[0]);
        a[r][1] = fmaf(-K2, row[1], vK[1]);
        a[r][2] = fmaf(-K2, row[2], vK[2]);
        a[r][3] = fmaf(-K2, row[3], vK[3]);
    }

    // block max per row
    float m8[8];
#pragma unroll
    for (int r = 0; r < 8; ++r)
        m8[r] = fmaxf(fmaxf(a[r][0], a[r][1]), fmaxf(a[r][2], a[r][3]));
#pragma unroll
    for (int off = 1; off < 64; off <<= 1)
#pragma unroll
        for (int r = 0; r < 8; ++r)
            m8[r] = fmaxf(m8[r], __shfl_xor(m8[r], off));
    __shared__ float wsm[8][8], wss[8][8];
    if (l == 0)
#pragma unroll
        for (int r = 0; r < 8; ++r) wsm[w][r] = m8[r];
    __syncthreads();
    float M8[8];
#pragma unroll
    for (int r = 0; r < 8; ++r) {
        float q0 = fmaxf(wsm[0][r], wsm[1][r]);
        float q1 = fmaxf(wsm[2][r], wsm[3][r]);
        float q2 = fmaxf(wsm[4][r], wsm[5][r]);
        float q3 = fmaxf(wsm[6][r], wsm[7][r]);
        M8[r] = fmaxf(fmaxf(q0, q1), fmaxf(q2, q3));
    }

    // block sum per row
    float s8[8];
#pragma unroll
    for (int r = 0; r < 8; ++r) {
        float t0 = fexp2(a[r][0] - M8[r]) + fexp2(a[r][1] - M8[r]);
        float t1 = fexp2(a[r][2] - M8[r]) + fexp2(a[r][3] - M8[r]);
        s8[r] = t0 + t1;
    }
#pragma unroll
    for (int off = 1; off < 64; off <<= 1)
#pragma unroll
        for (int r = 0; r < 8; ++r)
            s8[r] += __shfl_xor(s8[r], off);
    if (l == 0)
#pragma unroll
        for (int r = 0; r < 8; ++r) wss[w][r] = s8[r];
    __syncthreads();
    if (tid < 8) {
        float S = ((wss[0][tid] + wss[1][tid]) + (wss[2][tid] + wss[3][tid]))
                + ((wss[4][tid] + wss[5][tid]) + (wss[6][tid] + wss[7][tid]));
        float un = EPSF * (log_mu - LN2F * (M8[tid] + flog2(S)));
        du[r0 + tid] = fabsf(un - u[r0 + tid]);
        u[r0 + tid] = un;
    }
    if (blockIdx.x == 0 && tid == 0) flag[it] = 0.f;
}

// ---------------------------------------------------------------------------
// Kernel 3 (per iter, v half): v_j = eps*(log_nu - LSE_i((u_i - C_ij)/eps)).
// Identical shape on CT (aligned, in ws). Block 0 reduces du -> err[it].
// ---------------------------------------------------------------------------
__global__ __launch_bounds__(512) void sink_v(
        const float* __restrict__ CT, float* __restrict__ v,
        const float* __restrict__ u, const float* __restrict__ du,
        float* __restrict__ err, const float* __restrict__ flag,
        int it, float log_nu) {
    if (flag[it] != 0.f) return;
    int tid = threadIdx.x;
    int j0 = blockIdx.x * 8;
    int w = tid >> 6, l = tid & 63;

    float4 uu = *(const float4*)(u + 4 * tid);
    float uK[4] = { uu.x * K2, uu.y * K2, uu.z * K2, uu.w * K2 };

    float a[8][4];
#pragma unroll
    for (int r = 0; r < 8; ++r) {
        float4 ct = *(const float4*)(CT + (size_t)(j0 + r) * NN + 4 * tid);
        a[r][0] = fmaf(-K2, ct.x, uK[0]);
        a[r][1] = fmaf(-K2, ct.y, uK[1]);
        a[r][2] = fmaf(-K2, ct.z, uK[2]);
        a[r][3] = fmaf(-K2, ct.w, uK[3]);
    }

    float m8[8];
#pragma unroll
    for (int r = 0; r < 8; ++r)
        m8[r] = fmaxf(fmaxf(a[r][0], a[r][1]), fmaxf(a[r][2], a[r][3]));
#pragma unroll
    for (int off = 1; off < 64; off <<= 1)
#pragma unroll
        for (int r = 0; r < 8; ++r)
            m8[r] = fmaxf(m8[r], __shfl_xor(m8[r], off));
    __shared__ float wsm[8][8], wss[8][8];
    if (l == 0)
#pragma unroll
        for (int r = 0; r < 8; ++r) wsm[w][r] = m8[r];
    __syncthreads();
    float M8[8];
#pragma unroll
    for (int r = 0; r < 8; ++r) {
        float q0 = fmaxf(wsm[0][r], wsm[1][r]);
        float q1 = fmaxf(wsm[2][r], wsm[3][r]);
        float q2 = fmaxf(wsm[4][r], wsm[5][r]);
        float q3 = fmaxf(wsm[6][r], wsm[7][r]);
        M8[r] = fmaxf(fmaxf(q0, q1), fmaxf(q2, q3));
    }

    float s8[8];
#pragma unroll
    for (int r = 0; r < 8; ++r) {
        float t0 = fexp2(a[r][0] - M8[r]) + fexp2(a[r][1] - M8[r]);
        float t1 = fexp2(a[r][2] - M8[r]) + fexp2(a[r][3] - M8[r]);
        s8[r] = t0 + t1;
    }
#pragma unroll
    for (int off = 1; off < 64; off <<= 1)
#pragma unroll
        for (int r = 0; r < 8; ++r)
            s8[r] += __shfl_xor(s8[r], off);
    if (l == 0)
#pragma unroll
        for (int r = 0; r < 8; ++r) wss[w][r] = s8[r];
    __syncthreads();
    if (tid < 8) {
        float S = ((wss[0][tid] + wss[1][tid]) + (wss[2][tid] + wss[3][tid]))
                + ((wss[4][tid] + wss[5][tid]) + (wss[6][tid] + wss[7][tid]));
        v[j0 + tid] = EPSF * (log_nu - LN2F * (M8[tid] + flog2(S)));
    }

    if (blockIdx.x == 0) {
        float t = ((du[tid] + du[tid + 512]) + (du[tid + 1024] + du[tid + 1536]));
#pragma unroll
        for (int off = 1; off < 64; off <<= 1) t += __shfl_xor(t, off);
        __shared__ float sl[8];
        if (l == 0) sl[w] = t;
        __syncthreads();
        if (tid == 0)
            err[it] = ((sl[0] + sl[1]) + (sl[2] + sl[3]))
                    + ((sl[4] + sl[5]) + (sl[6] + sl[7]));
    }
}

// ---------------------------------------------------------------------------
// Kernel 4: pi = exp((-C+u+v)/eps), cost = sum(pi*C)
// grid 256 (8 rows per block), block 256. Scalar C reads (misaligned region).
// ---------------------------------------------------------------------------
__global__ __launch_bounds__(256) void sink_pi(
        const float* __restrict__ C, const float* __restrict__ u,
        const float* __restrict__ v, float* __restrict__ pi,
        float* __restrict__ cost) {
    int tid = threadIdx.x;
    const float4* v4 = (const float4*)v;
    float local = 0.f;
    for (int rr = 0; rr < 8; ++rr) {
        int i = blockIdx.x * 8 + rr;
        float ui = u[i];
        const float* row = C + (size_t)i * NN;
        float* prow = pi + (size_t)i * NN;
        for (int k = tid; k < NN / 4; k += 256) {
            float c0 = row[4 * k + 0], c1 = row[4 * k + 1];
            float c2 = row[4 * k + 2], c3 = row[4 * k + 3];
            float4 vv = v4[k];
            float p0 = fexp2((ui + vv.x - c0) * K2);
            float p1 = fexp2((ui + vv.y - c1) * K2);
            float p2 = fexp2((ui + vv.z - c2) * K2);
            float p3 = fexp2((ui + vv.w - c3) * K2);
            prow[4 * k + 0] = p0;
            prow[4 * k + 1] = p1;
            prow[4 * k + 2] = p2;
            prow[4 * k + 3] = p3;
            local = fmaf(p0, c0, local);
            local = fmaf(p1, c1, local);
            local = fmaf(p2, c2, local);
            local = fmaf(p3, c3, local);
        }
    }
#pragma unroll
    for (int off = 1; off < 64; off <<= 1) local += __shfl_xor(local, off);
    __shared__ float sl[4];
    if ((tid & 63) == 0) sl[tid >> 6] = local;
    __syncthreads();
    if (tid == 0) atomicAdd(cost, sl[0] + sl[1] + sl[2] + sl[3]);
}

extern "C" void kernel_launch(void* const* d_in, const int* in_sizes, int n_in,
                              void* d_out, int out_size, void* d_ws, size_t ws_size,
                              hipStream_t stream) {
    const float* x = (const float*)d_in[0];
    const float* y = (const float*)d_in[1];
    float* out  = (float*)d_out;
    float* cost = out;                       // [0]
    float* pi   = out + 1;                   // [1 .. 1+2048*2048)
    float* Cout = out + 1 + (size_t)NN * NN; // [.. 1+2*2048*2048)

    float* ws   = (float*)d_ws;
    float* u    = ws + U_OFF;
    float* v    = ws + V_OFF;
    float* err  = ws + ERR_OFF;
    float* flag = ws + FLG_OFF;
    float* du   = ws + DU_OFF;
    float* CT   = ws + CT_OFF;

    float log_mu = (float)log(1.0 / 2048.0 + 1e-8); // n == m -> log_nu == log_mu

    sink_cost<<<dim3(32, 16), 256, 0, stream>>>(x, y, Cout, CT, ws, cost);
    for (int it = 0; it < 10; ++it) {
        sink_u<<<256, 512, 0, stream>>>(Cout, u, v, du, err, flag, it, log_mu);
        sink_v<<<256, 512, 0, stream>>>(CT, v, u, du, err, flag, it, log_mu);
    }
    sink_pi<<<256, 256, 0, stream>>>(Cout, u, v, pi, cost);
}

// Round 10
// 131.148 us; speedup vs baseline: 5.9344x; 1.2405x over previous
//
#include <hip/hip_runtime.h>
#include <cmath>

#define NN 2048

#define EPSF 0.1f
#define K2 14.426950408889634f   /* (1/eps) * log2(e) */
#define LN2F 0.6931471805599453f

// ws layout (floats)
#define U_OFF   0
#define V_OFF   2048
#define ERR_OFF 4096
#define FLG_OFF 4112
#define DU_OFF  4128
#define CT_OFF  6176              // 2048*2048 transposed cost matrix

__device__ __forceinline__ float fexp2(float x) { return __builtin_amdgcn_exp2f(x); }
__device__ __forceinline__ float flog2(float x) { return __builtin_amdgcn_logf(x); }

// ---------------------------------------------------------------------------
// Kernel 1: one pass computes the 128x64 distance tile and writes BOTH
// Cout[i][j] (row-major, misaligned d_out region -> scalar stores) and
// CT[j][i] (aligned ws, coalesced float4 stores via LDS transpose through xs).
// Also zero-inits u/v/err/flag/du and cost. grid (32, 16), block 256.
// ---------------------------------------------------------------------------
__global__ __launch_bounds__(256) void sink_cost(
        const float* __restrict__ x, const float* __restrict__ y,
        float* __restrict__ Cout, float* __restrict__ CT,
        float* __restrict__ wsz, float* __restrict__ cost) {
    __shared__ float xs[128][65];
    __shared__ float ys[64][65];
    int tid = threadIdx.x;
    int bj = blockIdx.x, bi = blockIdx.y;

    if (bi == 0 && bj == 0) {
        // u(2048)+v(2048)+err(16)+flag(16)+du(2048) = 6176
        for (int k = tid; k < 6176; k += 256) wsz[k] = 0.f;
        if (tid == 0) cost[0] = 0.f;
    }

    const float4* x4 = (const float4*)x;
    const float4* y4 = (const float4*)y;
    for (int q = tid; q < 128 * 16; q += 256) {
        int r = q >> 4, dq = q & 15;
        float4 val = x4[(size_t)(bi * 128 + r) * 16 + dq];
        xs[r][dq * 4 + 0] = val.x; xs[r][dq * 4 + 1] = val.y;
        xs[r][dq * 4 + 2] = val.z; xs[r][dq * 4 + 3] = val.w;
    }
    for (int q = tid; q < 64 * 16; q += 256) {
        int r = q >> 4, dq = q & 15;
        float4 val = y4[(size_t)(bj * 64 + r) * 16 + dq];
        ys[r][dq * 4 + 0] = val.x; ys[r][dq * 4 + 1] = val.y;
        ys[r][dq * 4 + 2] = val.z; ys[r][dq * 4 + 3] = val.w;
    }
    __syncthreads();

    int tx = tid & 15, ty = tid >> 4;
    float acc[8][4];
#pragma unroll
    for (int ii = 0; ii < 8; ++ii)
#pragma unroll
        for (int jj = 0; jj < 4; ++jj) acc[ii][jj] = 0.f;

#pragma unroll 4
    for (int dd = 0; dd < 64; ++dd) {
        float xv[8], yv[4];
#pragma unroll
        for (int ii = 0; ii < 8; ++ii) xv[ii] = xs[ty + 16 * ii][dd];
#pragma unroll
        for (int jj = 0; jj < 4; ++jj) yv[jj] = ys[tx + 16 * jj][dd];
#pragma unroll
        for (int ii = 0; ii < 8; ++ii)
#pragma unroll
            for (int jj = 0; jj < 4; ++jj) {
                float d = xv[ii] - yv[jj];
                acc[ii][jj] = fmaf(d, d, acc[ii][jj]);
            }
    }

    // C (row-major) stores + stage tile into xs for the transpose
    __syncthreads();   // all compute reads of xs/ys done before overwrite
#pragma unroll
    for (int ii = 0; ii < 8; ++ii)
#pragma unroll
        for (int jj = 0; jj < 4; ++jj) {
            int ri = ty + 16 * ii;          // local row (x index)
            int cj = tx + 16 * jj;          // local col (y index)
            Cout[(size_t)(bi * 128 + ri) * NN + bj * 64 + cj] = acc[ii][jj];
            xs[ri][cj] = acc[ii][jj];
        }
    __syncthreads();

    // CT[j][i]: 64 rows x 128 cols per block; thread: row c = tid>>2,
    // cols rb..rb+31 (rb = (tid&3)*32). 512B contiguous per 4-lane group.
    int c = tid >> 2, rb = (tid & 3) * 32;
    float4* dst = (float4*)(CT + (size_t)(bj * 64 + c) * NN + bi * 128 + rb);
#pragma unroll
    for (int k = 0; k < 8; ++k) {
        dst[k] = make_float4(xs[rb + 4 * k + 0][c], xs[rb + 4 * k + 1][c],
                             xs[rb + 4 * k + 2][c], xs[rb + 4 * k + 3][c]);
    }
}

// ---------------------------------------------------------------------------
// Kernel 2 (per iter, u half): u_i = eps*(log_mu - LSE_j((v_j - C_ij)/eps)).
// grid 512, block 256 (2 blocks/CU). Block b: rows [4b,4b+4) of C (row-major
// in d_out, 4B-misaligned -> scalar dword loads). Thread t: cols {4t..4t+3,
// 1024+4t..1024+4t+3}. Writes u, du; publishes flag[it].
// ---------------------------------------------------------------------------
__global__ __launch_bounds__(256, 2) void sink_u(
        const float* __restrict__ C, float* __restrict__ u,
        const float* __restrict__ v, float* __restrict__ du,
        const float* __restrict__ err, float* __restrict__ flag,
        int it, float log_mu) {
    int tid = threadIdx.x;
    if (it > 0) {
        if (flag[it - 1] != 0.f || err[it - 1] < 0.1f) {
            if (blockIdx.x == 0 && tid == 0) flag[it] = 1.f;
            return;
        }
    }
    int r0 = blockIdx.x * 4;
    int w = tid >> 6, l = tid & 63;

    float4 va = *(const float4*)(v + 4 * tid);
    float4 vb = *(const float4*)(v + 1024 + 4 * tid);
    float vK[8] = { va.x * K2, va.y * K2, va.z * K2, va.w * K2,
                    vb.x * K2, vb.y * K2, vb.z * K2, vb.w * K2 };

    float a[4][8];
#pragma unroll
    for (int r = 0; r < 4; ++r) {
        const float* row = C + (size_t)(r0 + r) * NN + 4 * tid;
        a[r][0] = fmaf(-K2, row[0], vK[0]);
        a[r][1] = fmaf(-K2, row[1], vK[1]);
        a[r][2] = fmaf(-K2, row[2], vK[2]);
        a[r][3] = fmaf(-K2, row[3], vK[3]);
        a[r][4] = fmaf(-K2, row[1024], vK[4]);
        a[r][5] = fmaf(-K2, row[1025], vK[5]);
        a[r][6] = fmaf(-K2, row[1026], vK[6]);
        a[r][7] = fmaf(-K2, row[1027], vK[7]);
    }

    // block max per row
    float m4[4];
#pragma unroll
    for (int r = 0; r < 4; ++r) {
        float q0 = fmaxf(fmaxf(a[r][0], a[r][1]), fmaxf(a[r][2], a[r][3]));
        float q1 = fmaxf(fmaxf(a[r][4], a[r][5]), fmaxf(a[r][6], a[r][7]));
        m4[r] = fmaxf(q0, q1);
    }
#pragma unroll
    for (int off = 1; off < 64; off <<= 1)
#pragma unroll
        for (int r = 0; r < 4; ++r)
            m4[r] = fmaxf(m4[r], __shfl_xor(m4[r], off));
    __shared__ float wsm[4][4], wss[4][4];
    if (l == 0)
#pragma unroll
        for (int r = 0; r < 4; ++r) wsm[w][r] = m4[r];
    __syncthreads();
    float M4[4];
#pragma unroll
    for (int r = 0; r < 4; ++r)
        M4[r] = fmaxf(fmaxf(wsm[0][r], wsm[1][r]), fmaxf(wsm[2][r], wsm[3][r]));

    // block sum per row
    float s4[4];
#pragma unroll
    for (int r = 0; r < 4; ++r) {
        float t0 = fexp2(a[r][0] - M4[r]) + fexp2(a[r][1] - M4[r]);
        float t1 = fexp2(a[r][2] - M4[r]) + fexp2(a[r][3] - M4[r]);
        float t2 = fexp2(a[r][4] - M4[r]) + fexp2(a[r][5] - M4[r]);
        float t3 = fexp2(a[r][6] - M4[r]) + fexp2(a[r][7] - M4[r]);
        s4[r] = (t0 + t1) + (t2 + t3);
    }
#pragma unroll
    for (int off = 1; off < 64; off <<= 1)
#pragma unroll
        for (int r = 0; r < 4; ++r)
            s4[r] += __shfl_xor(s4[r], off);
    if (l == 0)
#pragma unroll
        for (int r = 0; r < 4; ++r) wss[w][r] = s4[r];
    __syncthreads();
    if (tid < 4) {
        float S = (wss[0][tid] + wss[1][tid]) + (wss[2][tid] + wss[3][tid]);
        float un = EPSF * (log_mu - LN2F * (M4[tid] + flog2(S)));
        du[r0 + tid] = fabsf(un - u[r0 + tid]);
        u[r0 + tid] = un;
    }
    if (blockIdx.x == 0 && tid == 0) flag[it] = 0.f;
}

// ---------------------------------------------------------------------------
// Kernel 3 (per iter, v half): v_j = eps*(log_nu - LSE_i((u_i - C_ij)/eps)).
// Identical shape on CT (aligned -> float4 loads). Block 0 reduces du->err.
// ---------------------------------------------------------------------------
__global__ __launch_bounds__(256, 2) void sink_v(
        const float* __restrict__ CT, float* __restrict__ v,
        const float* __restrict__ u, const float* __restrict__ du,
        float* __restrict__ err, const float* __restrict__ flag,
        int it, float log_nu) {
    if (flag[it] != 0.f) return;
    int tid = threadIdx.x;
    int j0 = blockIdx.x * 4;
    int w = tid >> 6, l = tid & 63;

    float4 ua = *(const float4*)(u + 4 * tid);
    float4 ub = *(const float4*)(u + 1024 + 4 * tid);
    float uK[8] = { ua.x * K2, ua.y * K2, ua.z * K2, ua.w * K2,
                    ub.x * K2, ub.y * K2, ub.z * K2, ub.w * K2 };

    float a[4][8];
#pragma unroll
    for (int r = 0; r < 4; ++r) {
        const float* row = CT + (size_t)(j0 + r) * NN;
        float4 c0 = *(const float4*)(row + 4 * tid);
        float4 c1 = *(const float4*)(row + 1024 + 4 * tid);
        a[r][0] = fmaf(-K2, c0.x, uK[0]);
        a[r][1] = fmaf(-K2, c0.y, uK[1]);
        a[r][2] = fmaf(-K2, c0.z, uK[2]);
        a[r][3] = fmaf(-K2, c0.w, uK[3]);
        a[r][4] = fmaf(-K2, c1.x, uK[4]);
        a[r][5] = fmaf(-K2, c1.y, uK[5]);
        a[r][6] = fmaf(-K2, c1.z, uK[6]);
        a[r][7] = fmaf(-K2, c1.w, uK[7]);
    }

    float m4[4];
#pragma unroll
    for (int r = 0; r < 4; ++r) {
        float q0 = fmaxf(fmaxf(a[r][0], a[r][1]), fmaxf(a[r][2], a[r][3]));
        float q1 = fmaxf(fmaxf(a[r][4], a[r][5]), fmaxf(a[r][6], a[r][7]));
        m4[r] = fmaxf(q0, q1);
    }
#pragma unroll
    for (int off = 1; off < 64; off <<= 1)
#pragma unroll
        for (int r = 0; r < 4; ++r)
            m4[r] = fmaxf(m4[r], __shfl_xor(m4[r], off));
    __shared__ float wsm[4][4], wss[4][4];
    if (l == 0)
#pragma unroll
        for (int r = 0; r < 4; ++r) wsm[w][r] = m4[r];
    __syncthreads();
    float M4[4];
#pragma unroll
    for (int r = 0; r < 4; ++r)
        M4[r] = fmaxf(fmaxf(wsm[0][r], wsm[1][r]), fmaxf(wsm[2][r], wsm[3][r]));

    float s4[4];
#pragma unroll
    for (int r = 0; r < 4; ++r) {
        float t0 = fexp2(a[r][0] - M4[r]) + fexp2(a[r][1] - M4[r]);
        float t1 = fexp2(a[r][2] - M4[r]) + fexp2(a[r][3] - M4[r]);
        float t2 = fexp2(a[r][4] - M4[r]) + fexp2(a[r][5] - M4[r]);
        float t3 = fexp2(a[r][6] - M4[r]) + fexp2(a[r][7] - M4[r]);
        s4[r] = (t0 + t1) + (t2 + t3);
    }
#pragma unroll
    for (int off = 1; off < 64; off <<= 1)
#pragma unroll
        for (int r = 0; r < 4; ++r)
            s4[r] += __shfl_xor(s4[r], off);
    if (l == 0)
#pragma unroll
        for (int r = 0; r < 4; ++r) wss[w][r] = s4[r];
    __syncthreads();
    if (tid < 4) {
        float S = (wss[0][tid] + wss[1][tid]) + (wss[2][tid] + wss[3][tid]);
        v[j0 + tid] = EPSF * (log_nu - LN2F * (M4[tid] + flog2(S)));
    }

    if (blockIdx.x == 0) {
        float t = 0.f;
#pragma unroll
        for (int k = 0; k < 8; ++k) t += du[tid + 256 * k];
#pragma unroll
        for (int off = 1; off < 64; off <<= 1) t += __shfl_xor(t, off);
        __shared__ float sl[4];
        if (l == 0) sl[w] = t;
        __syncthreads();
        if (tid == 0) err[it] = (sl[0] + sl[1]) + (sl[2] + sl[3]);
    }
}

// ---------------------------------------------------------------------------
// Kernel 4: pi = exp((-C+u+v)/eps), cost = sum(pi*C)
// grid 512 (4 rows per block), block 256 (2 waves/SIMD). Scalar C reads.
// ---------------------------------------------------------------------------
__global__ __launch_bounds__(256, 2) void sink_pi(
        const float* __restrict__ C, const float* __restrict__ u,
        const float* __restrict__ v, float* __restrict__ pi,
        float* __restrict__ cost) {
    int tid = threadIdx.x;
    const float4* v4 = (const float4*)v;
    float local = 0.f;
    for (int rr = 0; rr < 4; ++rr) {
        int i = blockIdx.x * 4 + rr;
        float ui = u[i];
        const float* row = C + (size_t)i * NN;
        float* prow = pi + (size_t)i * NN;
        for (int k = tid; k < NN / 4; k += 256) {
            float c0 = row[4 * k + 0], c1 = row[4 * k + 1];
            float c2 = row[4 * k + 2], c3 = row[4 * k + 3];
            float4 vv = v4[k];
            float p0 = fexp2((ui + vv.x - c0) * K2);
            float p1 = fexp2((ui + vv.y - c1) * K2);
            float p2 = fexp2((ui + vv.z - c2) * K2);
            float p3 = fexp2((ui + vv.w - c3) * K2);
            prow[4 * k + 0] = p0;
            prow[4 * k + 1] = p1;
            prow[4 * k + 2] = p2;
            prow[4 * k + 3] = p3;
            local = fmaf(p0, c0, local);
            local = fmaf(p1, c1, local);
            local = fmaf(p2, c2, local);
            local = fmaf(p3, c3, local);
        }
    }
#pragma unroll
    for (int off = 1; off < 64; off <<= 1) local += __shfl_xor(local, off);
    __shared__ float sl[4];
    if ((tid & 63) == 0) sl[tid >> 6] = local;
    __syncthreads();
    if (tid == 0) atomicAdd(cost, sl[0] + sl[1] + sl[2] + sl[3]);
}

extern "C" void kernel_launch(void* const* d_in, const int* in_sizes, int n_in,
                              void* d_out, int out_size, void* d_ws, size_t ws_size,
                              hipStream_t stream) {
    const float* x = (const float*)d_in[0];
    const float* y = (const float*)d_in[1];
    float* out  = (float*)d_out;
    float* cost = out;                       // [0]
    float* pi   = out + 1;                   // [1 .. 1+2048*2048)
    float* Cout = out + 1 + (size_t)NN * NN; // [.. 1+2*2048*2048)

    float* ws   = (float*)d_ws;
    float* u    = ws + U_OFF;
    float* v    = ws + V_OFF;
    float* err  = ws + ERR_OFF;
    float* flag = ws + FLG_OFF;
    float* du   = ws + DU_OFF;
    float* CT   = ws + CT_OFF;

    float log_mu = (float)log(1.0 / 2048.0 + 1e-8); // n == m -> log_nu == log_mu

    sink_cost<<<dim3(32, 16), 256, 0, stream>>>(x, y, Cout, CT, ws, cost);
    for (int it = 0; it < 10; ++it) {
        sink_u<<<512, 256, 0, stream>>>(Cout, u, v, du, err, flag, it, log_mu);
        sink_v<<<512, 256, 0, stream>>>(CT, v, u, du, err, flag, it, log_mu);
    }
    sink_pi<<<512, 256, 0, stream>>>(Cout, u, v, pi, cost);
}

// Round 11
// 126.295 us; speedup vs baseline: 6.1625x; 1.0384x over previous
//
#include <hip/hip_runtime.h>
#include <cmath>

#define NN 2048

#define EPSF 0.1f
#define K2 14.426950408889634f   /* (1/eps) * log2(e) */
#define LN2F 0.6931471805599453f

// ws layout (floats)
#define U_OFF   0
#define V_OFF   2048
#define ERR_OFF 4096
#define FLG_OFF 4112
#define DU_OFF  4128
#define CT_OFF  6176              // 2048*2048 transposed cost matrix

__device__ __forceinline__ float fexp2(float x) { return __builtin_amdgcn_exp2f(x); }
__device__ __forceinline__ float flog2(float x) { return __builtin_amdgcn_logf(x); }

// ---------------------------------------------------------------------------
// Kernel 1: C[i][j] = |x_i|^2 + |y_j|^2 - 2 x_i.y_j  (dot-product form; one
// fmaf per element-pair in the hot loop). Writes Cout (misaligned d_out,
// scalar stores) and CT (aligned ws, float4 stores via LDS transpose).
// Also zero-inits u/v/err/flag/du and cost. grid (32, 16), block 256.
// ---------------------------------------------------------------------------
__global__ __launch_bounds__(256) void sink_cost(
        const float* __restrict__ x, const float* __restrict__ y,
        float* __restrict__ Cout, float* __restrict__ CT,
        float* __restrict__ wsz, float* __restrict__ cost) {
    __shared__ float xs[128][65];
    __shared__ float ys[64][65];
    __shared__ float xn[128], yn[64];
    int tid = threadIdx.x;
    int bj = blockIdx.x, bi = blockIdx.y;

    if (bi == 0 && bj == 0) {
        // u(2048)+v(2048)+err(16)+flag(16)+du(2048) = 6176
        for (int k = tid; k < 6176; k += 256) wsz[k] = 0.f;
        if (tid == 0) cost[0] = 0.f;
    }

    const float4* x4 = (const float4*)x;
    const float4* y4 = (const float4*)y;
    for (int q = tid; q < 128 * 16; q += 256) {
        int r = q >> 4, dq = q & 15;
        float4 val = x4[(size_t)(bi * 128 + r) * 16 + dq];
        xs[r][dq * 4 + 0] = val.x; xs[r][dq * 4 + 1] = val.y;
        xs[r][dq * 4 + 2] = val.z; xs[r][dq * 4 + 3] = val.w;
    }
    for (int q = tid; q < 64 * 16; q += 256) {
        int r = q >> 4, dq = q & 15;
        float4 val = y4[(size_t)(bj * 64 + r) * 16 + dq];
        ys[r][dq * 4 + 0] = val.x; ys[r][dq * 4 + 1] = val.y;
        ys[r][dq * 4 + 2] = val.z; ys[r][dq * 4 + 3] = val.w;
    }
    __syncthreads();

    // cooperative row norms (waves 0-1: x, wave 2: y, wave 3 idle; one-shot)
    if (tid < 128) {
        float s = 0.f;
#pragma unroll 8
        for (int d = 0; d < 64; ++d) s = fmaf(xs[tid][d], xs[tid][d], s);
        xn[tid] = s;
    } else if (tid < 192) {
        int r = tid - 128;
        float s = 0.f;
#pragma unroll 8
        for (int d = 0; d < 64; ++d) s = fmaf(ys[r][d], ys[r][d], s);
        yn[r] = s;
    }
    __syncthreads();

    int tx = tid & 15, ty = tid >> 4;
    float acc[8][4];
#pragma unroll
    for (int ii = 0; ii < 8; ++ii)
#pragma unroll
        for (int jj = 0; jj < 4; ++jj) acc[ii][jj] = 0.f;

#pragma unroll 4
    for (int dd = 0; dd < 64; ++dd) {
        float xv[8], yv[4];
#pragma unroll
        for (int ii = 0; ii < 8; ++ii) xv[ii] = xs[ty + 16 * ii][dd];
#pragma unroll
        for (int jj = 0; jj < 4; ++jj) yv[jj] = ys[tx + 16 * jj][dd];
#pragma unroll
        for (int ii = 0; ii < 8; ++ii)
#pragma unroll
            for (int jj = 0; jj < 4; ++jj)
                acc[ii][jj] = fmaf(xv[ii], yv[jj], acc[ii][jj]);
    }

    // epilogue: c = xn + yn - 2*dot; store Cout + stage into xs for transpose
    float xnr[8], ynr[4];
#pragma unroll
    for (int ii = 0; ii < 8; ++ii) xnr[ii] = xn[ty + 16 * ii];
#pragma unroll
    for (int jj = 0; jj < 4; ++jj) ynr[jj] = yn[tx + 16 * jj];
    __syncthreads();   // all compute reads of xs/ys done before overwrite
#pragma unroll
    for (int ii = 0; ii < 8; ++ii)
#pragma unroll
        for (int jj = 0; jj < 4; ++jj) {
            int ri = ty + 16 * ii;          // local row (x index)
            int cj = tx + 16 * jj;          // local col (y index)
            float c = fmaf(-2.f, acc[ii][jj], xnr[ii] + ynr[jj]);
            Cout[(size_t)(bi * 128 + ri) * NN + bj * 64 + cj] = c;
            xs[ri][cj] = c;
        }
    __syncthreads();

    // CT[j][i]: 64 rows x 128 cols per block; thread: row c = tid>>2,
    // cols rb..rb+31 (rb = (tid&3)*32). 512B contiguous per 4-lane group.
    int c = tid >> 2, rb = (tid & 3) * 32;
    float4* dst = (float4*)(CT + (size_t)(bj * 64 + c) * NN + bi * 128 + rb);
#pragma unroll
    for (int k = 0; k < 8; ++k) {
        dst[k] = make_float4(xs[rb + 4 * k + 0][c], xs[rb + 4 * k + 1][c],
                             xs[rb + 4 * k + 2][c], xs[rb + 4 * k + 3][c]);
    }
}

// ---------------------------------------------------------------------------
// Kernel 2 (per iter, u half): u_i = eps*(log_mu - LSE_j((v_j - C_ij)/eps)).
// grid 1024, block 256 (4 blocks/CU). Block b: rows [2b,2b+2) of C (row-major
// in d_out, 4B-misaligned -> scalar dword loads). Thread t: cols {4t..4t+3,
// 1024+4t..1024+4t+3}. Writes u, du; publishes flag[it].
// ---------------------------------------------------------------------------
__global__ __launch_bounds__(256, 4) void sink_u(
        const float* __restrict__ C, float* __restrict__ u,
        const float* __restrict__ v, float* __restrict__ du,
        const float* __restrict__ err, float* __restrict__ flag,
        int it, float log_mu) {
    int tid = threadIdx.x;
    if (it > 0) {
        if (flag[it - 1] != 0.f || err[it - 1] < 0.1f) {
            if (blockIdx.x == 0 && tid == 0) flag[it] = 1.f;
            return;
        }
    }
    int r0 = blockIdx.x * 2;
    int w = tid >> 6, l = tid & 63;

    float4 va = *(const float4*)(v + 4 * tid);
    float4 vb = *(const float4*)(v + 1024 + 4 * tid);
    float vK[8] = { va.x * K2, va.y * K2, va.z * K2, va.w * K2,
                    vb.x * K2, vb.y * K2, vb.z * K2, vb.w * K2 };

    float a[2][8];
#pragma unroll
    for (int r = 0; r < 2; ++r) {
        const float* row = C + (size_t)(r0 + r) * NN + 4 * tid;
        a[r][0] = fmaf(-K2, row[0], vK[0]);
        a[r][1] = fmaf(-K2, row[1], vK[1]);
        a[r][2] = fmaf(-K2, row[2], vK[2]);
        a[r][3] = fmaf(-K2, row[3], vK[3]);
        a[r][4] = fmaf(-K2, row[1024], vK[4]);
        a[r][5] = fmaf(-K2, row[1025], vK[5]);
        a[r][6] = fmaf(-K2, row[1026], vK[6]);
        a[r][7] = fmaf(-K2, row[1027], vK[7]);
    }

    // block max per row
    float m2[2];
#pragma unroll
    for (int r = 0; r < 2; ++r) {
        float q0 = fmaxf(fmaxf(a[r][0], a[r][1]), fmaxf(a[r][2], a[r][3]));
        float q1 = fmaxf(fmaxf(a[r][4], a[r][5]), fmaxf(a[r][6], a[r][7]));
        m2[r] = fmaxf(q0, q1);
    }
#pragma unroll
    for (int off = 1; off < 64; off <<= 1)
#pragma unroll
        for (int r = 0; r < 2; ++r)
            m2[r] = fmaxf(m2[r], __shfl_xor(m2[r], off));
    __shared__ float wsm[4][2], wss[4][2];
    if (l == 0)
#pragma unroll
        for (int r = 0; r < 2; ++r) wsm[w][r] = m2[r];
    __syncthreads();
    float M2[2];
#pragma unroll
    for (int r = 0; r < 2; ++r)
        M2[r] = fmaxf(fmaxf(wsm[0][r], wsm[1][r]), fmaxf(wsm[2][r], wsm[3][r]));

    // block sum per row
    float s2[2];
#pragma unroll
    for (int r = 0; r < 2; ++r) {
        float t0 = fexp2(a[r][0] - M2[r]) + fexp2(a[r][1] - M2[r]);
        float t1 = fexp2(a[r][2] - M2[r]) + fexp2(a[r][3] - M2[r]);
        float t2 = fexp2(a[r][4] - M2[r]) + fexp2(a[r][5] - M2[r]);
        float t3 = fexp2(a[r][6] - M2[r]) + fexp2(a[r][7] - M2[r]);
        s2[r] = (t0 + t1) + (t2 + t3);
    }
#pragma unroll
    for (int off = 1; off < 64; off <<= 1)
#pragma unroll
        for (int r = 0; r < 2; ++r)
            s2[r] += __shfl_xor(s2[r], off);
    if (l == 0)
#pragma unroll
        for (int r = 0; r < 2; ++r) wss[w][r] = s2[r];
    __syncthreads();
    if (tid < 2) {
        float S = (wss[0][tid] + wss[1][tid]) + (wss[2][tid] + wss[3][tid]);
        float un = EPSF * (log_mu - LN2F * (M2[tid] + flog2(S)));
        du[r0 + tid] = fabsf(un - u[r0 + tid]);
        u[r0 + tid] = un;
    }
    if (blockIdx.x == 0 && tid == 0) flag[it] = 0.f;
}

// ---------------------------------------------------------------------------
// Kernel 3 (per iter, v half): v_j = eps*(log_nu - LSE_i((u_i - C_ij)/eps)).
// Identical shape on CT (aligned -> float4 loads). Block 0 reduces du->err.
// ---------------------------------------------------------------------------
__global__ __launch_bounds__(256, 4) void sink_v(
        const float* __restrict__ CT, float* __restrict__ v,
        const float* __restrict__ u, const float* __restrict__ du,
        float* __restrict__ err, const float* __restrict__ flag,
        int it, float log_nu) {
    if (flag[it] != 0.f) return;
    int tid = threadIdx.x;
    int j0 = blockIdx.x * 2;
    int w = tid >> 6, l = tid & 63;

    float4 ua = *(const float4*)(u + 4 * tid);
    float4 ub = *(const float4*)(u + 1024 + 4 * tid);
    float uK[8] = { ua.x * K2, ua.y * K2, ua.z * K2, ua.w * K2,
                    ub.x * K2, ub.y * K2, ub.z * K2, ub.w * K2 };

    float a[2][8];
#pragma unroll
    for (int r = 0; r < 2; ++r) {
        const float* row = CT + (size_t)(j0 + r) * NN;
        float4 c0 = *(const float4*)(row + 4 * tid);
        float4 c1 = *(const float4*)(row + 1024 + 4 * tid);
        a[r][0] = fmaf(-K2, c0.x, uK[0]);
        a[r][1] = fmaf(-K2, c0.y, uK[1]);
        a[r][2] = fmaf(-K2, c0.z, uK[2]);
        a[r][3] = fmaf(-K2, c0.w, uK[3]);
        a[r][4] = fmaf(-K2, c1.x, uK[4]);
        a[r][5] = fmaf(-K2, c1.y, uK[5]);
        a[r][6] = fmaf(-K2, c1.z, uK[6]);
        a[r][7] = fmaf(-K2, c1.w, uK[7]);
    }

    float m2[2];
#pragma unroll
    for (int r = 0; r < 2; ++r) {
        float q0 = fmaxf(fmaxf(a[r][0], a[r][1]), fmaxf(a[r][2], a[r][3]));
        float q1 = fmaxf(fmaxf(a[r][4], a[r][5]), fmaxf(a[r][6], a[r][7]));
        m2[r] = fmaxf(q0, q1);
    }
#pragma unroll
    for (int off = 1; off < 64; off <<= 1)
#pragma unroll
        for (int r = 0; r < 2; ++r)
            m2[r] = fmaxf(m2[r], __shfl_xor(m2[r], off));
    __shared__ float wsm[4][2], wss[4][2];
    if (l == 0)
#pragma unroll
        for (int r = 0; r < 2; ++r) wsm[w][r] = m2[r];
    __syncthreads();
    float M2[2];
#pragma unroll
    for (int r = 0; r < 2; ++r)
        M2[r] = fmaxf(fmaxf(wsm[0][r], wsm[1][r]), fmaxf(wsm[2][r], wsm[3][r]));

    float s2[2];
#pragma unroll
    for (int r = 0; r < 2; ++r) {
        float t0 = fexp2(a[r][0] - M2[r]) + fexp2(a[r][1] - M2[r]);
        float t1 = fexp2(a[r][2] - M2[r]) + fexp2(a[r][3] - M2[r]);
        float t2 = fexp2(a[r][4] - M2[r]) + fexp2(a[r][5] - M2[r]);
        float t3 = fexp2(a[r][6] - M2[r]) + fexp2(a[r][7] - M2[r]);
        s2[r] = (t0 + t1) + (t2 + t3);
    }
#pragma unroll
    for (int off = 1; off < 64; off <<= 1)
#pragma unroll
        for (int r = 0; r < 2; ++r)
            s2[r] += __shfl_xor(s2[r], off);
    if (l == 0)
#pragma unroll
        for (int r = 0; r < 2; ++r) wss[w][r] = s2[r];
    __syncthreads();
    if (tid < 2) {
        float S = (wss[0][tid] + wss[1][tid]) + (wss[2][tid] + wss[3][tid]);
        v[j0 + tid] = EPSF * (log_nu - LN2F * (M2[tid] + flog2(S)));
    }

    if (blockIdx.x == 0) {
        float t = 0.f;
#pragma unroll
        for (int k = 0; k < 8; ++k) t += du[tid + 256 * k];
#pragma unroll
        for (int off = 1; off < 64; off <<= 1) t += __shfl_xor(t, off);
        __shared__ float sl[4];
        if (l == 0) sl[w] = t;
        __syncthreads();
        if (tid == 0) err[it] = (sl[0] + sl[1]) + (sl[2] + sl[3]);
    }
}

// ---------------------------------------------------------------------------
// Kernel 4: pi = exp((-C+u+v)/eps), cost = sum(pi*C)
// grid 512 (4 rows per block), block 256 (2 blocks/CU). Scalar C reads.
// ---------------------------------------------------------------------------
__global__ __launch_bounds__(256, 2) void sink_pi(
        const float* __restrict__ C, const float* __restrict__ u,
        const float* __restrict__ v, float* __restrict__ pi,
        float* __restrict__ cost) {
    int tid = threadIdx.x;
    const float4* v4 = (const float4*)v;
    float local = 0.f;
    for (int rr = 0; rr < 4; ++rr) {
        int i = blockIdx.x * 4 + rr;
        float ui = u[i];
        const float* row = C + (size_t)i * NN;
        float* prow = pi + (size_t)i * NN;
        for (int k = tid; k < NN / 4; k += 256) {
            float c0 = row[4 * k + 0], c1 = row[4 * k + 1];
            float c2 = row[4 * k + 2], c3 = row[4 * k + 3];
            float4 vv = v4[k];
            float p0 = fexp2((ui + vv.x - c0) * K2);
            float p1 = fexp2((ui + vv.y - c1) * K2);
            float p2 = fexp2((ui + vv.z - c2) * K2);
            float p3 = fexp2((ui + vv.w - c3) * K2);
            prow[4 * k + 0] = p0;
            prow[4 * k + 1] = p1;
            prow[4 * k + 2] = p2;
            prow[4 * k + 3] = p3;
            local = fmaf(p0, c0, local);
            local = fmaf(p1, c1, local);
            local = fmaf(p2, c2, local);
            local = fmaf(p3, c3, local);
        }
    }
#pragma unroll
    for (int off = 1; off < 64; off <<= 1) local += __shfl_xor(local, off);
    __shared__ float sl[4];
    if ((tid & 63) == 0) sl[tid >> 6] = local;
    __syncthreads();
    if (tid == 0) atomicAdd(cost, sl[0] + sl[1] + sl[2] + sl[3]);
}

extern "C" void kernel_launch(void* const* d_in, const int* in_sizes, int n_in,
                              void* d_out, int out_size, void* d_ws, size_t ws_size,
                              hipStream_t stream) {
    const float* x = (const float*)d_in[0];
    const float* y = (const float*)d_in[1];
    float* out  = (float*)d_out;
    float* cost = out;                       // [0]
    float* pi   = out + 1;                   // [1 .. 1+2048*2048)
    float* Cout = out + 1 + (size_t)NN * NN; // [.. 1+2*2048*2048)

    float* ws   = (float*)d_ws;
    float* u    = ws + U_OFF;
    float* v    = ws + V_OFF;
    float* err  = ws + ERR_OFF;
    float* flag = ws + FLG_OFF;
    float* du   = ws + DU_OFF;
    float* CT   = ws + CT_OFF;

    float log_mu = (float)log(1.0 / 2048.0 + 1e-8); // n == m -> log_nu == log_mu

    sink_cost<<<dim3(32, 16), 256, 0, stream>>>(x, y, Cout, CT, ws, cost);
    for (int it = 0; it < 10; ++it) {
        sink_u<<<1024, 256, 0, stream>>>(Cout, u, v, du, err, flag, it, log_mu);
        sink_v<<<1024, 256, 0, stream>>>(CT, v, u, du, err, flag, it, log_mu);
    }
    sink_pi<<<512, 256, 0, stream>>>(Cout, u, v, pi, cost);
}